// Round 4
// baseline (451.403 us; speedup 1.0000x reference)
//
#include <hip/hip_runtime.h>

#define B_ 16
#define C_ 256
#define N_ 2048
#define CK_ 64

using f32x4  = __attribute__((ext_vector_type(4))) float;
using bf16x8 = __attribute__((ext_vector_type(8))) short;
using short4_t = __attribute__((ext_vector_type(4))) short;

static __device__ __forceinline__ float bf2f(short s){
  unsigned u = ((unsigned)(unsigned short)s) << 16;
  float f; __builtin_memcpy(&f, &u, 4); return f;
}
static __device__ __forceinline__ short f2bf(float f){
  unsigned u; __builtin_memcpy(&u, &f, 4);
  unsigned r = (u + 0x7fffu + ((u >> 16) & 1u)) >> 16;   // RNE
  return (short)(unsigned short)r;
}

// ---------------- K0: weights -> bf16 (Wb rows: [0,64)=Wq, [64,128)=Wk, [128,384)=Wv)
__global__ void k_convw(const float* __restrict__ Wq, const float* __restrict__ Wk,
                        const float* __restrict__ Wv, const float* __restrict__ Wl,
                        short* __restrict__ Wb, short* __restrict__ Wlb){
  int i = blockIdx.x*256 + threadIdx.x;
  if(i < 384*C_){
    int o = i >> 8;
    float v;
    if(o < 64)       v = Wq[i];
    else if(o < 128) v = Wk[i - 64*C_];
    else             v = Wv[i - 128*C_];
    Wb[i] = f2bf(v);
  }
  if(i < C_*C_) Wlb[i] = f2bf(Wl[i]);
}

// ---------------- K1a: xsum[b,c] = sum_n x[b,c,n]  (f64, wave-per-row, 1024 blocks)
__global__ void k_xsum(const float* __restrict__ x, double* __restrict__ xsum){
  int b = blockIdx.y;
  int c = blockIdx.x*4 + (threadIdx.x>>6);
  int l = threadIdx.x & 63;
  const float* row = x + ((size_t)b*C_ + c)*N_;
  double s = 0.0;
  #pragma unroll
  for(int it = 0; it < 8; ++it){
    f32x4 v = *(const f32x4*)(row + it*256 + l*4);
    s += (double)v[0] + (double)v[1] + (double)v[2] + (double)v[3];
  }
  for(int off = 32; off; off >>= 1) s += __shfl_down(s, off);
  if(l == 0) xsum[b*C_ + c] = s;
}

// ---------------- K1b: g[b,:] = Wk^T (Wq xsum)   (f64 exact colsum prep, tiny)
__global__ void k_prep_g2(const double* __restrict__ xsum, const float* __restrict__ Wq,
                          const float* __restrict__ Wk, double* __restrict__ g){
  int b = blockIdx.x;
  __shared__ double xs[C_];
  __shared__ double t[CK_];
  int tid = threadIdx.x;
  xs[tid] = xsum[b*C_ + tid];
  __syncthreads();
  if(tid < CK_){
    double s = 0.0;
    const float* wr = Wq + (size_t)tid*C_;
    for(int c = 0; c < C_; ++c) s += (double)wr[c]*xs[c];
    t[tid] = s;
  }
  __syncthreads();
  double s = 0.0;
  for(int j = 0; j < CK_; ++j) s += (double)Wk[(size_t)j*C_ + tid]*t[j];
  g[b*C_ + tid] = s;
}

// ---------------- K2: inv[b,m] = 1/(1e-9 + dot(g[b,:], x[b,:,m]))   (f64 accumulate)
__global__ void k_colsum(const float* __restrict__ x, const double* __restrict__ g,
                         float* __restrict__ inv){
  int b = blockIdx.y;
  int m = blockIdx.x*256 + threadIdx.x;
  __shared__ double gs[C_];
  gs[threadIdx.x] = g[b*C_ + threadIdx.x];
  __syncthreads();
  const float* xb = x + (size_t)b*C_*N_ + m;
  double s = 0.0;
  #pragma unroll 4
  for(int c = 0; c < C_; ++c) s += gs[c]*(double)xb[(size_t)c*N_];
  inv[b*N_ + m] = (float)(1.0/(1e-9 + s));
}

// ---------------- K3: qk[b][n][0..64)=q, [64..128)=k ; vT[b][c'][n] = v*inv (all bf16)
__global__ __launch_bounds__(256,2) void k_qkv(const float* __restrict__ x,
        const short* __restrict__ Wb, const float* __restrict__ inv,
        short* __restrict__ qk, short* __restrict__ vT){
  int b = blockIdx.y; int n0 = blockIdx.x*64;
  int tid = threadIdx.x, w = tid>>6, l = tid&63, lo = l&15, g = l>>4;
  __shared__ short xT[64][40];                 // [n][c-chunk], 80B rows
  const float* xb = x + (size_t)b*C_*N_;
  f32x4 acc[6][4];
  #pragma unroll
  for(int oi=0;oi<6;++oi) for(int nj=0;nj<4;++nj) acc[oi][nj]=(f32x4){0.f,0.f,0.f,0.f};
  for(int cc = 0; cc < C_; cc += 32){
    __syncthreads();
    #pragma unroll
    for(int kk = 0; kk < 4; ++kk){             // stage x^T (pair-packed b32 writes)
      int pp = w + 4*kk;
      int ci = cc + 2*pp;
      float a  = xb[(size_t)ci*N_ + n0 + l];
      float c2 = xb[(size_t)(ci+1)*N_ + n0 + l];
      unsigned pr = (unsigned)(unsigned short)f2bf(a) | (((unsigned)(unsigned short)f2bf(c2))<<16);
      *(unsigned*)(&xT[l][2*pp]) = pr;
    }
    __syncthreads();
    bf16x8 bfr[4];
    #pragma unroll
    for(int nj = 0; nj < 4; ++nj) bfr[nj] = *(const bf16x8*)(&xT[nj*16 + lo][8*g]);
    #pragma unroll
    for(int oi = 0; oi < 6; ++oi){
      int o = w*96 + oi*16 + lo;
      bf16x8 af = *(const bf16x8*)(Wb + (size_t)o*C_ + cc + 8*g);
      #pragma unroll
      for(int nj = 0; nj < 4; ++nj)
        acc[oi][nj] = __builtin_amdgcn_mfma_f32_16x16x32_bf16(af, bfr[nj], acc[oi][nj], 0,0,0);
    }
  }
  #pragma unroll
  for(int oi = 0; oi < 6; ++oi){
    int obase = w*96 + oi*16;
    for(int nj = 0; nj < 4; ++nj){
      int n = n0 + nj*16 + lo;
      if(obase < 128){
        short4_t pk;
        #pragma unroll
        for(int r = 0; r < 4; ++r) pk[r] = f2bf(acc[oi][nj][r]);
        *(short4_t*)(&qk[((size_t)b*N_ + n)*128 + obase + 4*g]) = pk;
      } else {
        float iv = inv[b*N_ + n];
        #pragma unroll
        for(int r = 0; r < 4; ++r){
          int o = obase + 4*g + r;
          vT[((size_t)b*C_ + (o-128))*N_ + n] = f2bf(acc[oi][nj][r]*iv);
        }
      }
    }
  }
}

// ---------------- K4: attention, single-pass (no max), swapped QK^T, no barriers.
// block = 128 rows (4 waves x 32 rows); grid 256 linear with XCD swizzle.
__global__ __launch_bounds__(256,1) void k_attn(const short* __restrict__ qk,
                                                const short* __restrict__ vT,
                                                short* __restrict__ att){
  int d = blockIdx.x;                  // 256 blocks; wg->XCD assumed d%8
  int j = d >> 3;                      // 0..31
  int b = (d & 7)*2 + (j >> 4);        // 2 batches per XCD (L2 locality)
  int n0 = (j & 15)*128;
  int tid = threadIdx.x;
  int w = tid>>6, l = tid&63, lo = l&15, g = l>>4;

  __shared__ short p_lds[4][32][40];   // per-wave p tile [n][m], 80B rows

  const short* qkb = qk + (size_t)b*N_*128;
  const short* vtb = vT + (size_t)b*C_*N_;

  // Q fragments (B-operand of swapped QK^T): lane lo -> row n
  bf16x8 qa[2][2];
  #pragma unroll
  for(int rt = 0; rt < 2; ++rt){
    int n = n0 + w*32 + rt*16 + lo;
    const short* qrow = qkb + (size_t)n*128;
    qa[rt][0] = *(const bf16x8*)(qrow + 8*g);
    qa[rt][1] = *(const bf16x8*)(qrow + 32 + 8*g);
  }

  f32x4 oacc[2][16];
  #pragma unroll
  for(int rt=0;rt<2;++rt) for(int cj=0;cj<16;++cj) oacc[rt][cj]=(f32x4){0.f,0.f,0.f,0.f};
  float srow[2] = {0.f, 0.f};          // per-lane partial row-sum (row n = lo)

  for(int mc = 0; mc < N_/32; ++mc){
    int m0 = mc*32;
    // ---- QK^T swapped: mfma(K, Q) -> lane lo = n, reg 4g+r = m
    float pe[2][2][4];
    #pragma unroll
    for(int tau = 0; tau < 2; ++tau){
      const short* krow = qkb + (size_t)(m0 + tau*16 + lo)*128 + 64;
      bf16x8 kb0 = *(const bf16x8*)(krow + 8*g);
      bf16x8 kb1 = *(const bf16x8*)(krow + 32 + 8*g);
      #pragma unroll
      for(int rt = 0; rt < 2; ++rt){
        f32x4 a = (f32x4){0.f,0.f,0.f,0.f};
        a = __builtin_amdgcn_mfma_f32_16x16x32_bf16(kb0, qa[rt][0], a, 0,0,0);
        a = __builtin_amdgcn_mfma_f32_16x16x32_bf16(kb1, qa[rt][1], a, 0,0,0);
        #pragma unroll
        for(int r = 0; r < 4; ++r) pe[rt][tau][r] = __expf(a[r] - 12.f);
      }
    }
    // ---- row-sum accumulate + p -> LDS (one b64 per rt,tau: 4 contiguous m)
    #pragma unroll
    for(int rt = 0; rt < 2; ++rt){
      #pragma unroll
      for(int tau = 0; tau < 2; ++tau){
        srow[rt] += pe[rt][tau][0] + pe[rt][tau][1] + pe[rt][tau][2] + pe[rt][tau][3];
        short4_t pk;
        #pragma unroll
        for(int r = 0; r < 4; ++r) pk[r] = f2bf(pe[rt][tau][r]);
        *(short4_t*)(&p_lds[w][rt*16 + lo][tau*16 + 4*g]) = pk;
      }
    }
    // ---- PV: A = p (rows n), B = v'^T rows c direct from global (L1/L2-hot)
    bf16x8 pa0 = *(const bf16x8*)(&p_lds[w][lo][8*g]);
    bf16x8 pa1 = *(const bf16x8*)(&p_lds[w][16 + lo][8*g]);
    #pragma unroll
    for(int cj = 0; cj < 16; ++cj){
      bf16x8 bv = *(const bf16x8*)(vtb + (size_t)(cj*16 + lo)*N_ + m0 + 8*g);
      oacc[0][cj] = __builtin_amdgcn_mfma_f32_16x16x32_bf16(pa0, bv, oacc[0][cj], 0,0,0);
      oacc[1][cj] = __builtin_amdgcn_mfma_f32_16x16x32_bf16(pa1, bv, oacc[1][cj], 0,0,0);
    }
  }

  // ---- row-sum completion: combine the 4 g-groups (lanes lo, lo+16, lo+32, lo+48)
  float rinvs[2][4];
  #pragma unroll
  for(int rt = 0; rt < 2; ++rt){
    float S = srow[rt];
    S += __shfl_xor(S, 16);
    S += __shfl_xor(S, 32);
    float ri = 1.f/(S + 1e-30f);       // rinv for row n = lo (lanes 0..15 authoritative)
    #pragma unroll
    for(int r = 0; r < 4; ++r) rinvs[rt][r] = __shfl(ri, 4*g + r);
  }

  short* attb = att + (size_t)b*N_*C_;
  #pragma unroll
  for(int rt = 0; rt < 2; ++rt)
    for(int cj = 0; cj < 16; ++cj)
      #pragma unroll
      for(int r = 0; r < 4; ++r){
        int n = n0 + w*32 + rt*16 + 4*g + r;
        attb[(size_t)n*C_ + cj*16 + lo] = f2bf(oacc[rt][cj][r]*rinvs[rt][r]);
      }
}

// ---------------- K5: h[b][n][o] = sum_c Wl[o,c]*(x[c,n]-att[n,c]); BN partial sums
__global__ __launch_bounds__(256,2) void k_hgemm(const float* __restrict__ x,
        const short* __restrict__ att, const short* __restrict__ Wlb,
        short* __restrict__ h, float* __restrict__ bnsum, float* __restrict__ bnssq){
  int b = blockIdx.y; int n0 = blockIdx.x*64;
  int tid = threadIdx.x, w = tid>>6, l = tid&63, lo = l&15, g = l>>4;
  __shared__ short rT[64][40];
  const float* xb = x + (size_t)b*C_*N_;
  const short* attb = att + (size_t)b*N_*C_;
  f32x4 acc[4][4];
  #pragma unroll
  for(int ot=0;ot<4;++ot) for(int nj=0;nj<4;++nj) acc[ot][nj]=(f32x4){0.f,0.f,0.f,0.f};
  for(int cc = 0; cc < C_; cc += 32){
    __syncthreads();
    #pragma unroll
    for(int kk = 0; kk < 4; ++kk){
      int pp = w + 4*kk;
      int ci = cc + 2*pp;
      float a  = xb[(size_t)ci*N_ + n0 + l];
      float c2 = xb[(size_t)(ci+1)*N_ + n0 + l];
      unsigned pr = (unsigned)(unsigned short)f2bf(a) | (((unsigned)(unsigned short)f2bf(c2))<<16);
      *(unsigned*)(&rT[l][2*pp]) = pr;
    }
    __syncthreads();
    {   // r = x - att (LDS RMW, b128)
      int n = tid>>2, ii = tid&3;
      bf16x8 av = *(const bf16x8*)(attb + (size_t)(n0+n)*C_ + cc + 8*ii);
      bf16x8* pr = (bf16x8*)(&rT[n][8*ii]);
      bf16x8 xv = *pr, rv;
      #pragma unroll
      for(int j = 0; j < 8; ++j) rv[j] = f2bf(bf2f(xv[j]) - bf2f(av[j]));
      *pr = rv;
    }
    __syncthreads();
    bf16x8 bfr[4];
    #pragma unroll
    for(int nj = 0; nj < 4; ++nj) bfr[nj] = *(const bf16x8*)(&rT[nj*16 + lo][8*g]);
    #pragma unroll
    for(int ot = 0; ot < 4; ++ot){
      int o = w*64 + ot*16 + lo;
      bf16x8 af = *(const bf16x8*)(Wlb + (size_t)o*C_ + cc + 8*g);
      #pragma unroll
      for(int nj = 0; nj < 4; ++nj)
        acc[ot][nj] = __builtin_amdgcn_mfma_f32_16x16x32_bf16(af, bfr[nj], acc[ot][nj], 0,0,0);
    }
  }
  short* hb = h + (size_t)b*N_*C_;
  #pragma unroll
  for(int ot = 0; ot < 4; ++ot)
    for(int nj = 0; nj < 4; ++nj){
      int n = n0 + nj*16 + lo;
      short4_t pk;
      #pragma unroll
      for(int r = 0; r < 4; ++r) pk[r] = f2bf(acc[ot][nj][r]);
      *(short4_t*)(&hb[(size_t)n*C_ + w*64 + ot*16 + 4*g]) = pk;
    }
  #pragma unroll
  for(int ot = 0; ot < 4; ++ot){
    float s4[4] = {0,0,0,0}, q4[4] = {0,0,0,0};
    for(int nj = 0; nj < 4; ++nj)
      #pragma unroll
      for(int r = 0; r < 4; ++r){ float v = acc[ot][nj][r]; s4[r] += v; q4[r] += v*v; }
    #pragma unroll
    for(int r = 0; r < 4; ++r){
      float ss = s4[r], qq = q4[r];
      for(int msk = 1; msk < 16; msk <<= 1){ ss += __shfl_xor(ss, msk); qq += __shfl_xor(qq, msk); }
      if(lo == 0){
        int o = w*64 + ot*16 + 4*g + r;
        atomicAdd(&bnsum[o], ss);
        atomicAdd(&bnssq[o], qq);
      }
    }
  }
}

// ---------------- K6: BN finalize -> scale/shift per channel
__global__ void k_bnfin(const float* __restrict__ bnsum, const float* __restrict__ bnssq,
                        const float* __restrict__ gamma, const float* __restrict__ beta,
                        float* __restrict__ bnsc, float* __restrict__ bnsh){
  int o = threadIdx.x;
  float cnt = (float)(B_*N_);
  float mean = bnsum[o]/cnt;
  float var  = bnssq[o]/cnt - mean*mean;
  float is   = rsqrtf(var + 1e-5f);
  float sc   = gamma[o]*is;
  bnsc[o] = sc;
  bnsh[o] = beta[o] - mean*sc;
}

// ---------------- K7: out[c][n] = x + relu(h*sc+sh)  (LDS transpose of h[n][o])
__global__ void k_final(const float* __restrict__ x, const short* __restrict__ h,
                        const float* __restrict__ bnsc, const float* __restrict__ bnsh,
                        float* __restrict__ out){
  int b = blockIdx.z, c0 = blockIdx.y*64, n0 = blockIdx.x*64;
  int tid = threadIdx.x;
  __shared__ float ht[64][65];
  {
    int n = tid>>2, ii = tid&3;
    #pragma unroll
    for(int p = 0; p < 2; ++p){
      int coff = 32*p + 8*ii;
      bf16x8 hv = *(const bf16x8*)(h + ((size_t)(b*N_ + n0 + n))*C_ + c0 + coff);
      #pragma unroll
      for(int j = 0; j < 8; ++j) ht[n][coff + j] = bf2f(hv[j]);
    }
  }
  __syncthreads();
  int c = tid>>2, i2 = tid&3;
  float sc = bnsc[c0 + c], sh = bnsh[c0 + c];
  const float* xr = x + ((size_t)b*C_ + c0 + c)*N_ + n0 + 16*i2;
  float* orow = out + ((size_t)b*C_ + c0 + c)*N_ + n0 + 16*i2;
  #pragma unroll
  for(int k = 0; k < 16; k += 4){
    f32x4 xv = *(const f32x4*)(xr + k);
    f32x4 ov;
    #pragma unroll
    for(int j = 0; j < 4; ++j){
      float bn = ht[16*i2 + k + j][c]*sc + sh;
      ov[j] = xv[j] + fmaxf(bn, 0.f);
    }
    *(f32x4*)(orow + k) = ov;
  }
}

extern "C" void kernel_launch(void* const* d_in, const int* in_sizes, int n_in,
                              void* d_out, int out_size, void* d_ws, size_t ws_size,
                              hipStream_t stream){
  const float* x     = (const float*)d_in[0];
  const float* Wq    = (const float*)d_in[1];
  const float* Wk    = (const float*)d_in[2];
  const float* Wv    = (const float*)d_in[3];
  const float* Wl    = (const float*)d_in[4];
  const float* gamma = (const float*)d_in[5];
  const float* beta  = (const float*)d_in[6];
  float* out = (float*)d_out;

  char* p = (char*)d_ws;
  double* g    = (double*)p; p += (size_t)B_*C_*8;
  double* xsum = (double*)p; p += (size_t)B_*C_*8;
  float* inv  = (float*)p;  p += (size_t)B_*N_*4;
  short* Wb   = (short*)p;  p += (size_t)384*C_*2;
  short* Wlb  = (short*)p;  p += (size_t)C_*C_*2;
  short* qk   = (short*)p;  p += (size_t)B_*N_*128*2;
  short* vT   = (short*)p;  p += (size_t)B_*C_*N_*2;
  short* att  = (short*)p;  p += (size_t)B_*N_*C_*2;
  short* h    = (short*)p;  p += (size_t)B_*N_*C_*2;
  float* bnsum= (float*)p;  p += C_*4;
  float* bnssq= (float*)p;  p += C_*4;
  float* bnsc = (float*)p;  p += C_*4;
  float* bnsh = (float*)p;  p += C_*4;

  hipMemsetAsync(bnsum, 0, 2*C_*sizeof(float), stream);

  k_convw  <<<384, 256, 0, stream>>>(Wq, Wk, Wv, Wl, Wb, Wlb);
  k_xsum   <<<dim3(C_/4, B_), 256, 0, stream>>>(x, xsum);
  k_prep_g2<<<B_, 256, 0, stream>>>(xsum, Wq, Wk, g);
  k_colsum <<<dim3(N_/256, B_), 256, 0, stream>>>(x, g, inv);
  k_qkv    <<<dim3(N_/64, B_), 256, 0, stream>>>(x, Wb, inv, qk, vT);
  k_attn   <<<256, 256, 0, stream>>>(qk, vT, att);
  k_hgemm  <<<dim3(N_/64, B_), 256, 0, stream>>>(x, att, Wlb, h, bnsum, bnssq);
  k_bnfin  <<<1, 256, 0, stream>>>(bnsum, bnssq, gamma, beta, bnsc, bnsh);
  k_final  <<<dim3(N_/64, C_/64, B_), 256, 0, stream>>>(x, h, bnsc, bnsh, out);
}

// Round 5
// 248.745 us; speedup vs baseline: 1.8147x; 1.8147x over previous
//
#include <hip/hip_runtime.h>

#define B_ 16
#define C_ 256
#define N_ 2048
#define CK_ 64

using f32x4  = __attribute__((ext_vector_type(4))) float;
using bf16x8 = __attribute__((ext_vector_type(8))) short;
using short4_t = __attribute__((ext_vector_type(4))) short;

static __device__ __forceinline__ float bf2f(short s){
  unsigned u = ((unsigned)(unsigned short)s) << 16;
  float f; __builtin_memcpy(&f, &u, 4); return f;
}
static __device__ __forceinline__ short f2bf(float f){
  unsigned u; __builtin_memcpy(&u, &f, 4);
  unsigned r = (u + 0x7fffu + ((u >> 16) & 1u)) >> 16;   // RNE
  return (short)(unsigned short)r;
}

// ---------------- K0: weights -> bf16 (Wb rows: [0,64)=Wq, [64,128)=Wk, [128,384)=Wv)
__global__ void k_convw(const float* __restrict__ Wq, const float* __restrict__ Wk,
                        const float* __restrict__ Wv, const float* __restrict__ Wl,
                        short* __restrict__ Wb, short* __restrict__ Wlb){
  int i = blockIdx.x*256 + threadIdx.x;
  if(i < 384*C_){
    int o = i >> 8;
    float v;
    if(o < 64)       v = Wq[i];
    else if(o < 128) v = Wk[i - 64*C_];
    else             v = Wv[i - 128*C_];
    Wb[i] = f2bf(v);
  }
  if(i < C_*C_) Wlb[i] = f2bf(Wl[i]);
}

// ---------------- K1a: xsum[b,c] = sum_n x[b,c,n]  (f64, wave-per-row, 1024 blocks)
__global__ void k_xsum(const float* __restrict__ x, double* __restrict__ xsum){
  int b = blockIdx.y;
  int c = blockIdx.x*4 + (threadIdx.x>>6);
  int l = threadIdx.x & 63;
  const float* row = x + ((size_t)b*C_ + c)*N_;
  double s = 0.0;
  #pragma unroll
  for(int it = 0; it < 8; ++it){
    f32x4 v = *(const f32x4*)(row + it*256 + l*4);
    s += (double)v[0] + (double)v[1] + (double)v[2] + (double)v[3];
  }
  for(int off = 32; off; off >>= 1) s += __shfl_down(s, off);
  if(l == 0) xsum[b*C_ + c] = s;
}

// ---------------- K1b: g[b,:] = Wk^T (Wq xsum)   (f64 exact colsum prep, tiny)
__global__ void k_prep_g2(const double* __restrict__ xsum, const float* __restrict__ Wq,
                          const float* __restrict__ Wk, double* __restrict__ g){
  int b = blockIdx.x;
  __shared__ double xs[C_];
  __shared__ double t[CK_];
  int tid = threadIdx.x;
  xs[tid] = xsum[b*C_ + tid];
  __syncthreads();
  if(tid < CK_){
    double s = 0.0;
    const float* wr = Wq + (size_t)tid*C_;
    for(int c = 0; c < C_; ++c) s += (double)wr[c]*xs[c];
    t[tid] = s;
  }
  __syncthreads();
  double s = 0.0;
  for(int j = 0; j < CK_; ++j) s += (double)Wk[(size_t)j*C_ + tid]*t[j];
  g[b*C_ + tid] = s;
}

// ---------------- K2: inv[b,m] = 1/(1e-9 + dot(g[b,:], x[b,:,m]))   (f64 accumulate)
__global__ void k_colsum(const float* __restrict__ x, const double* __restrict__ g,
                         float* __restrict__ inv){
  int b = blockIdx.y;
  int m = blockIdx.x*256 + threadIdx.x;
  __shared__ double gs[C_];
  gs[threadIdx.x] = g[b*C_ + threadIdx.x];
  __syncthreads();
  const float* xb = x + (size_t)b*C_*N_ + m;
  double s = 0.0;
  #pragma unroll 4
  for(int c = 0; c < C_; ++c) s += gs[c]*(double)xb[(size_t)c*N_];
  inv[b*N_ + m] = (float)(1.0/(1e-9 + s));
}

// ---------------- K3: qk[b][n][0..64)=q, [64..128)=k ; vT[b][c'][n] = v*inv (all bf16)
__global__ __launch_bounds__(256,2) void k_qkv(const float* __restrict__ x,
        const short* __restrict__ Wb, const float* __restrict__ inv,
        short* __restrict__ qk, short* __restrict__ vT){
  int b = blockIdx.y; int n0 = blockIdx.x*64;
  int tid = threadIdx.x, w = tid>>6, l = tid&63, lo = l&15, g = l>>4;
  __shared__ short xT[64][40];                 // [n][c-chunk], 80B rows
  const float* xb = x + (size_t)b*C_*N_;
  f32x4 acc[6][4];
  #pragma unroll
  for(int oi=0;oi<6;++oi) for(int nj=0;nj<4;++nj) acc[oi][nj]=(f32x4){0.f,0.f,0.f,0.f};
  for(int cc = 0; cc < C_; cc += 32){
    __syncthreads();
    #pragma unroll
    for(int kk = 0; kk < 4; ++kk){             // stage x^T (pair-packed b32 writes)
      int pp = w + 4*kk;
      int ci = cc + 2*pp;
      float a  = xb[(size_t)ci*N_ + n0 + l];
      float c2 = xb[(size_t)(ci+1)*N_ + n0 + l];
      unsigned pr = (unsigned)(unsigned short)f2bf(a) | (((unsigned)(unsigned short)f2bf(c2))<<16);
      *(unsigned*)(&xT[l][2*pp]) = pr;
    }
    __syncthreads();
    bf16x8 bfr[4];
    #pragma unroll
    for(int nj = 0; nj < 4; ++nj) bfr[nj] = *(const bf16x8*)(&xT[nj*16 + lo][8*g]);
    #pragma unroll
    for(int oi = 0; oi < 6; ++oi){
      int o = w*96 + oi*16 + lo;
      bf16x8 af = *(const bf16x8*)(Wb + (size_t)o*C_ + cc + 8*g);
      #pragma unroll
      for(int nj = 0; nj < 4; ++nj)
        acc[oi][nj] = __builtin_amdgcn_mfma_f32_16x16x32_bf16(af, bfr[nj], acc[oi][nj], 0,0,0);
    }
  }
  #pragma unroll
  for(int oi = 0; oi < 6; ++oi){
    int obase = w*96 + oi*16;
    for(int nj = 0; nj < 4; ++nj){
      int n = n0 + nj*16 + lo;
      if(obase < 128){
        short4_t pk;
        #pragma unroll
        for(int r = 0; r < 4; ++r) pk[r] = f2bf(acc[oi][nj][r]);
        *(short4_t*)(&qk[((size_t)b*N_ + n)*128 + obase + 4*g]) = pk;
      } else {
        float iv = inv[b*N_ + n];
        #pragma unroll
        for(int r = 0; r < 4; ++r){
          int o = obase + 4*g + r;
          vT[((size_t)b*C_ + (o-128))*N_ + n] = f2bf(acc[oi][nj][r]*iv);
        }
      }
    }
  }
}

// ---------------- K4: attention, single-pass, LDS-staged V, block = 64 rows (4 waves
// x 16 rows QK^T; PV repartitioned wave->64 columns). grid 512, 2 blocks/CU.
__global__ __launch_bounds__(256,2) void k_attn(const short* __restrict__ qk,
                                                const short* __restrict__ vT,
                                                short* __restrict__ att){
  int d = blockIdx.x;                  // 512 blocks; wg->XCD assumed d%8
  int xcd = d & 7, j = d >> 3;         // j: 0..63
  int b = xcd*2 + (j >> 5);            // 2 batches per XCD (L2 locality)
  int n0 = (j & 31)*64;
  int tid = threadIdx.x;
  int w = tid>>6, l = tid&63, lo = l&15, g = l>>4;

  __shared__ short vt_lds[C_][40];     // [c'][32 m], 80B rows (2-way banks = free)
  __shared__ short p_lds[64][40];      // block-shared p tile [n][m]
  __shared__ float rs_lds[64];

  const short* qkb = qk + (size_t)b*N_*128;
  const short* vtb = vT + (size_t)b*C_*N_;

  // Q fragment (B-operand of swapped QK^T): wave's 16 rows, n = n0 + w*16 + lo
  const short* qrow = qkb + (size_t)(n0 + w*16 + lo)*128;
  bf16x8 qa0 = *(const bf16x8*)(qrow + 8*g);
  bf16x8 qa1 = *(const bf16x8*)(qrow + 32 + 8*g);

  f32x4 oacc[4][4];                    // [rt rows][jj cols], cols = w*64..w*64+63
  #pragma unroll
  for(int rt=0;rt<4;++rt) for(int jj=0;jj<4;++jj) oacc[rt][jj]=(f32x4){0.f,0.f,0.f,0.f};
  float srow = 0.f;                    // row-sum for n = w*16 + lo (partial over g)

  int cp = tid>>2, ii = tid&3;         // V staging: row cp+64k, 16B at m0+8*ii

  for(int mc = 0; mc < N_/32; ++mc){
    int m0 = mc*32;
    // -- issue global loads early: latency hides under barrier + QK^T
    bf16x8 vstg[4];
    #pragma unroll
    for(int kk = 0; kk < 4; ++kk)
      vstg[kk] = *(const bf16x8*)(vtb + (size_t)(cp + 64*kk)*N_ + m0 + 8*ii);
    bf16x8 kb[2][2];
    #pragma unroll
    for(int tau = 0; tau < 2; ++tau){
      const short* krow = qkb + (size_t)(m0 + tau*16 + lo)*128 + 64;
      kb[tau][0] = *(const bf16x8*)(krow + 8*g);
      kb[tau][1] = *(const bf16x8*)(krow + 32 + 8*g);
    }
    __syncthreads();                   // prev iter's p/V LDS reads complete
    // -- QK^T swapped: D[m on regs 4g+r][n on lanes lo]
    #pragma unroll
    for(int tau = 0; tau < 2; ++tau){
      f32x4 a = (f32x4){0.f,0.f,0.f,0.f};
      a = __builtin_amdgcn_mfma_f32_16x16x32_bf16(kb[tau][0], qa0, a, 0,0,0);
      a = __builtin_amdgcn_mfma_f32_16x16x32_bf16(kb[tau][1], qa1, a, 0,0,0);
      short4_t pk;
      #pragma unroll
      for(int r = 0; r < 4; ++r){
        float pe = __expf(a[r] - 12.f);
        srow += pe;
        pk[r] = f2bf(pe);
      }
      *(short4_t*)(&p_lds[w*16 + lo][tau*16 + 4*g]) = pk;
    }
    // -- stage V to LDS (b128 writes, 2-way banks)
    #pragma unroll
    for(int kk = 0; kk < 4; ++kk)
      *(bf16x8*)(&vt_lds[cp + 64*kk][8*ii]) = vstg[kk];
    __syncthreads();                   // p + V visible
    // -- PV: wave computes all 64 rows x its 64 cols (8 LDS reads, 16 MFMAs)
    bf16x8 pa[4], bv[4];
    #pragma unroll
    for(int rt = 0; rt < 4; ++rt) pa[rt] = *(const bf16x8*)(&p_lds[rt*16 + lo][8*g]);
    #pragma unroll
    for(int jj = 0; jj < 4; ++jj) bv[jj] = *(const bf16x8*)(&vt_lds[(w*4+jj)*16 + lo][8*g]);
    #pragma unroll
    for(int rt = 0; rt < 4; ++rt)
      #pragma unroll
      for(int jj = 0; jj < 4; ++jj)
        oacc[rt][jj] = __builtin_amdgcn_mfma_f32_16x16x32_bf16(pa[rt], bv[jj], oacc[rt][jj], 0,0,0);
  }

  // -- finalize row sums: combine g-groups, share across waves via LDS
  float S = srow;
  S += __shfl_xor(S, 16);
  S += __shfl_xor(S, 32);
  if(l < 16) rs_lds[w*16 + l] = 1.f/(S + 1e-30f);
  __syncthreads();
  float rinvs[4][4];
  #pragma unroll
  for(int rt = 0; rt < 4; ++rt)
    #pragma unroll
    for(int r = 0; r < 4; ++r) rinvs[rt][r] = rs_lds[rt*16 + 4*g + r];

  short* attb = att + (size_t)b*N_*C_;
  #pragma unroll
  for(int rt = 0; rt < 4; ++rt)
    #pragma unroll
    for(int jj = 0; jj < 4; ++jj)
      #pragma unroll
      for(int r = 0; r < 4; ++r){
        int n = n0 + rt*16 + 4*g + r;
        int c = w*64 + jj*16 + lo;
        attb[(size_t)n*C_ + c] = f2bf(oacc[rt][jj][r]*rinvs[rt][r]);
      }
}

// ---------------- K5: h[b][n][o] = sum_c Wl[o,c]*(x[c,n]-att[n,c]); BN partial sums
__global__ __launch_bounds__(256,2) void k_hgemm(const float* __restrict__ x,
        const short* __restrict__ att, const short* __restrict__ Wlb,
        short* __restrict__ h, float* __restrict__ bnsum, float* __restrict__ bnssq){
  int b = blockIdx.y; int n0 = blockIdx.x*64;
  int tid = threadIdx.x, w = tid>>6, l = tid&63, lo = l&15, g = l>>4;
  __shared__ short rT[64][40];
  const float* xb = x + (size_t)b*C_*N_;
  const short* attb = att + (size_t)b*N_*C_;
  f32x4 acc[4][4];
  #pragma unroll
  for(int ot=0;ot<4;++ot) for(int nj=0;nj<4;++nj) acc[ot][nj]=(f32x4){0.f,0.f,0.f,0.f};
  for(int cc = 0; cc < C_; cc += 32){
    __syncthreads();
    #pragma unroll
    for(int kk = 0; kk < 4; ++kk){
      int pp = w + 4*kk;
      int ci = cc + 2*pp;
      float a  = xb[(size_t)ci*N_ + n0 + l];
      float c2 = xb[(size_t)(ci+1)*N_ + n0 + l];
      unsigned pr = (unsigned)(unsigned short)f2bf(a) | (((unsigned)(unsigned short)f2bf(c2))<<16);
      *(unsigned*)(&rT[l][2*pp]) = pr;
    }
    __syncthreads();
    {   // r = x - att (LDS RMW, b128)
      int n = tid>>2, ii = tid&3;
      bf16x8 av = *(const bf16x8*)(attb + (size_t)(n0+n)*C_ + cc + 8*ii);
      bf16x8* pr = (bf16x8*)(&rT[n][8*ii]);
      bf16x8 xv = *pr, rv;
      #pragma unroll
      for(int j = 0; j < 8; ++j) rv[j] = f2bf(bf2f(xv[j]) - bf2f(av[j]));
      *pr = rv;
    }
    __syncthreads();
    bf16x8 bfr[4];
    #pragma unroll
    for(int nj = 0; nj < 4; ++nj) bfr[nj] = *(const bf16x8*)(&rT[nj*16 + lo][8*g]);
    #pragma unroll
    for(int ot = 0; ot < 4; ++ot){
      int o = w*64 + ot*16 + lo;
      bf16x8 af = *(const bf16x8*)(Wlb + (size_t)o*C_ + cc + 8*g);
      #pragma unroll
      for(int nj = 0; nj < 4; ++nj)
        acc[ot][nj] = __builtin_amdgcn_mfma_f32_16x16x32_bf16(af, bfr[nj], acc[ot][nj], 0,0,0);
    }
  }
  short* hb = h + (size_t)b*N_*C_;
  #pragma unroll
  for(int ot = 0; ot < 4; ++ot)
    for(int nj = 0; nj < 4; ++nj){
      int n = n0 + nj*16 + lo;
      short4_t pk;
      #pragma unroll
      for(int r = 0; r < 4; ++r) pk[r] = f2bf(acc[ot][nj][r]);
      *(short4_t*)(&hb[(size_t)n*C_ + w*64 + ot*16 + 4*g]) = pk;
    }
  #pragma unroll
  for(int ot = 0; ot < 4; ++ot){
    float s4[4] = {0,0,0,0}, q4[4] = {0,0,0,0};
    for(int nj = 0; nj < 4; ++nj)
      #pragma unroll
      for(int r = 0; r < 4; ++r){ float v = acc[ot][nj][r]; s4[r] += v; q4[r] += v*v; }
    #pragma unroll
    for(int r = 0; r < 4; ++r){
      float ss = s4[r], qq = q4[r];
      for(int msk = 1; msk < 16; msk <<= 1){ ss += __shfl_xor(ss, msk); qq += __shfl_xor(qq, msk); }
      if(lo == 0){
        int o = w*64 + ot*16 + 4*g + r;
        atomicAdd(&bnsum[o], ss);
        atomicAdd(&bnssq[o], qq);
      }
    }
  }
}

// ---------------- K6: BN finalize -> scale/shift per channel
__global__ void k_bnfin(const float* __restrict__ bnsum, const float* __restrict__ bnssq,
                        const float* __restrict__ gamma, const float* __restrict__ beta,
                        float* __restrict__ bnsc, float* __restrict__ bnsh){
  int o = threadIdx.x;
  float cnt = (float)(B_*N_);
  float mean = bnsum[o]/cnt;
  float var  = bnssq[o]/cnt - mean*mean;
  float is   = rsqrtf(var + 1e-5f);
  float sc   = gamma[o]*is;
  bnsc[o] = sc;
  bnsh[o] = beta[o] - mean*sc;
}

// ---------------- K7: out[c][n] = x + relu(h*sc+sh)  (LDS transpose of h[n][o])
__global__ void k_final(const float* __restrict__ x, const short* __restrict__ h,
                        const float* __restrict__ bnsc, const float* __restrict__ bnsh,
                        float* __restrict__ out){
  int b = blockIdx.z, c0 = blockIdx.y*64, n0 = blockIdx.x*64;
  int tid = threadIdx.x;
  __shared__ float ht[64][65];
  {
    int n = tid>>2, ii = tid&3;
    #pragma unroll
    for(int p = 0; p < 2; ++p){
      int coff = 32*p + 8*ii;
      bf16x8 hv = *(const bf16x8*)(h + ((size_t)(b*N_ + n0 + n))*C_ + c0 + coff);
      #pragma unroll
      for(int j = 0; j < 8; ++j) ht[n][coff + j] = bf2f(hv[j]);
    }
  }
  __syncthreads();
  int c = tid>>2, i2 = tid&3;
  float sc = bnsc[c0 + c], sh = bnsh[c0 + c];
  const float* xr = x + ((size_t)b*C_ + c0 + c)*N_ + n0 + 16*i2;
  float* orow = out + ((size_t)b*C_ + c0 + c)*N_ + n0 + 16*i2;
  #pragma unroll
  for(int k = 0; k < 16; k += 4){
    f32x4 xv = *(const f32x4*)(xr + k);
    f32x4 ov;
    #pragma unroll
    for(int j = 0; j < 4; ++j){
      float bn = ht[16*i2 + k + j][c]*sc + sh;
      ov[j] = xv[j] + fmaxf(bn, 0.f);
    }
    *(f32x4*)(orow + k) = ov;
  }
}

extern "C" void kernel_launch(void* const* d_in, const int* in_sizes, int n_in,
                              void* d_out, int out_size, void* d_ws, size_t ws_size,
                              hipStream_t stream){
  const float* x     = (const float*)d_in[0];
  const float* Wq    = (const float*)d_in[1];
  const float* Wk    = (const float*)d_in[2];
  const float* Wv    = (const float*)d_in[3];
  const float* Wl    = (const float*)d_in[4];
  const float* gamma = (const float*)d_in[5];
  const float* beta  = (const float*)d_in[6];
  float* out = (float*)d_out;

  char* p = (char*)d_ws;
  double* g    = (double*)p; p += (size_t)B_*C_*8;
  double* xsum = (double*)p; p += (size_t)B_*C_*8;
  float* inv  = (float*)p;  p += (size_t)B_*N_*4;
  short* Wb   = (short*)p;  p += (size_t)384*C_*2;
  short* Wlb  = (short*)p;  p += (size_t)C_*C_*2;
  short* qk   = (short*)p;  p += (size_t)B_*N_*128*2;
  short* vT   = (short*)p;  p += (size_t)B_*C_*N_*2;
  short* att  = (short*)p;  p += (size_t)B_*N_*C_*2;
  short* h    = (short*)p;  p += (size_t)B_*N_*C_*2;
  float* bnsum= (float*)p;  p += C_*4;
  float* bnssq= (float*)p;  p += C_*4;
  float* bnsc = (float*)p;  p += C_*4;
  float* bnsh = (float*)p;  p += C_*4;

  hipMemsetAsync(bnsum, 0, 2*C_*sizeof(float), stream);

  k_convw  <<<384, 256, 0, stream>>>(Wq, Wk, Wv, Wl, Wb, Wlb);
  k_xsum   <<<dim3(C_/4, B_), 256, 0, stream>>>(x, xsum);
  k_prep_g2<<<B_, 256, 0, stream>>>(xsum, Wq, Wk, g);
  k_colsum <<<dim3(N_/256, B_), 256, 0, stream>>>(x, g, inv);
  k_qkv    <<<dim3(N_/64, B_), 256, 0, stream>>>(x, Wb, inv, qk, vT);
  k_attn   <<<512, 256, 0, stream>>>(qk, vT, att);
  k_hgemm  <<<dim3(N_/64, B_), 256, 0, stream>>>(x, att, Wlb, h, bnsum, bnssq);
  k_bnfin  <<<1, 256, 0, stream>>>(bnsum, bnssq, gamma, beta, bnsc, bnsh);
  k_final  <<<dim3(N_/64, C_/64, B_), 256, 0, stream>>>(x, h, bnsc, bnsh, out);
}

// Round 6
// 241.614 us; speedup vs baseline: 1.8683x; 1.0295x over previous
//
#include <hip/hip_runtime.h>

#define B_ 16
#define C_ 256
#define N_ 2048
#define CK_ 64

using f32x4  = __attribute__((ext_vector_type(4))) float;
using bf16x8 = __attribute__((ext_vector_type(8))) short;
using short4_t = __attribute__((ext_vector_type(4))) short;

static __device__ __forceinline__ float bf2f(short s){
  unsigned u = ((unsigned)(unsigned short)s) << 16;
  float f; __builtin_memcpy(&f, &u, 4); return f;
}
static __device__ __forceinline__ short f2bf(float f){
  unsigned u; __builtin_memcpy(&u, &f, 4);
  unsigned r = (u + 0x7fffu + ((u >> 16) & 1u)) >> 16;   // RNE
  return (short)(unsigned short)r;
}

// ---------------- K0: weights -> bf16 (Wb rows: [0,64)=Wq, [64,128)=Wk, [128,384)=Wv)
__global__ void k_convw(const float* __restrict__ Wq, const float* __restrict__ Wk,
                        const float* __restrict__ Wv, const float* __restrict__ Wl,
                        short* __restrict__ Wb, short* __restrict__ Wlb){
  int i = blockIdx.x*256 + threadIdx.x;
  if(i < 384*C_){
    int o = i >> 8;
    float v;
    if(o < 64)       v = Wq[i];
    else if(o < 128) v = Wk[i - 64*C_];
    else             v = Wv[i - 128*C_];
    Wb[i] = f2bf(v);
  }
  if(i < C_*C_) Wlb[i] = f2bf(Wl[i]);
}

// ---------------- K1a: xsum[b,c] = sum_n x[b,c,n]  (f64, wave-per-row, 1024 blocks)
__global__ void k_xsum(const float* __restrict__ x, double* __restrict__ xsum){
  int b = blockIdx.y;
  int c = blockIdx.x*4 + (threadIdx.x>>6);
  int l = threadIdx.x & 63;
  const float* row = x + ((size_t)b*C_ + c)*N_;
  double s = 0.0;
  #pragma unroll
  for(int it = 0; it < 8; ++it){
    f32x4 v = *(const f32x4*)(row + it*256 + l*4);
    s += (double)v[0] + (double)v[1] + (double)v[2] + (double)v[3];
  }
  for(int off = 32; off; off >>= 1) s += __shfl_down(s, off);
  if(l == 0) xsum[b*C_ + c] = s;
}

// ---------------- K1b: g[b,:] = Wk^T (Wq xsum)   (f64 exact colsum prep, tiny)
__global__ void k_prep_g2(const double* __restrict__ xsum, const float* __restrict__ Wq,
                          const float* __restrict__ Wk, double* __restrict__ g){
  int b = blockIdx.x;
  __shared__ double xs[C_];
  __shared__ double t[CK_];
  int tid = threadIdx.x;
  xs[tid] = xsum[b*C_ + tid];
  __syncthreads();
  if(tid < CK_){
    double s = 0.0;
    const float* wr = Wq + (size_t)tid*C_;
    for(int c = 0; c < C_; ++c) s += (double)wr[c]*xs[c];
    t[tid] = s;
  }
  __syncthreads();
  double s = 0.0;
  for(int j = 0; j < CK_; ++j) s += (double)Wk[(size_t)j*C_ + tid]*t[j];
  g[b*C_ + tid] = s;
}

// ---------------- K2: inv[b,m] = 1/(1e-9 + dot(g[b,:], x[b,:,m]))   (f64, c split 2-way)
__global__ void k_colsum(const float* __restrict__ x, const double* __restrict__ g,
                         float* __restrict__ inv){
  int b = blockIdx.y;
  int m = blockIdx.x*128 + (threadIdx.x & 127);
  int ch = threadIdx.x >> 7;
  __shared__ double gs[C_];
  __shared__ double part[256];
  gs[threadIdx.x] = g[b*C_ + threadIdx.x];
  __syncthreads();
  const float* xb = x + (size_t)b*C_*N_ + m;
  double s = 0.0;
  #pragma unroll 4
  for(int c = ch*128; c < ch*128 + 128; ++c) s += gs[c]*(double)xb[(size_t)c*N_];
  part[threadIdx.x] = s;
  __syncthreads();
  if(threadIdx.x < 128)
    inv[b*N_ + m] = (float)(1.0/(1e-9 + part[threadIdx.x] + part[threadIdx.x + 128]));
}

// ---------------- K3: qk[b][n][0..64)=q, [64..128)=k ; vT[b][c'][n] = v*inv (all bf16)
__global__ __launch_bounds__(256,2) void k_qkv(const float* __restrict__ x,
        const short* __restrict__ Wb, const float* __restrict__ inv,
        short* __restrict__ qk, short* __restrict__ vT){
  int b = blockIdx.y; int n0 = blockIdx.x*64;
  int tid = threadIdx.x, w = tid>>6, l = tid&63, lo = l&15, g = l>>4;
  __shared__ short xT[64][40];                 // [n][c-chunk], 80B rows
  const float* xb = x + (size_t)b*C_*N_;
  f32x4 acc[6][4];
  #pragma unroll
  for(int oi=0;oi<6;++oi) for(int nj=0;nj<4;++nj) acc[oi][nj]=(f32x4){0.f,0.f,0.f,0.f};
  for(int cc = 0; cc < C_; cc += 32){
    __syncthreads();
    #pragma unroll
    for(int kk = 0; kk < 4; ++kk){             // stage x^T (pair-packed b32 writes)
      int pp = w + 4*kk;
      int ci = cc + 2*pp;
      float a  = xb[(size_t)ci*N_ + n0 + l];
      float c2 = xb[(size_t)(ci+1)*N_ + n0 + l];
      unsigned pr = (unsigned)(unsigned short)f2bf(a) | (((unsigned)(unsigned short)f2bf(c2))<<16);
      *(unsigned*)(&xT[l][2*pp]) = pr;
    }
    __syncthreads();
    bf16x8 bfr[4];
    #pragma unroll
    for(int nj = 0; nj < 4; ++nj) bfr[nj] = *(const bf16x8*)(&xT[nj*16 + lo][8*g]);
    #pragma unroll
    for(int oi = 0; oi < 6; ++oi){
      int o = w*96 + oi*16 + lo;
      bf16x8 af = *(const bf16x8*)(Wb + (size_t)o*C_ + cc + 8*g);
      #pragma unroll
      for(int nj = 0; nj < 4; ++nj)
        acc[oi][nj] = __builtin_amdgcn_mfma_f32_16x16x32_bf16(af, bfr[nj], acc[oi][nj], 0,0,0);
    }
  }
  #pragma unroll
  for(int oi = 0; oi < 6; ++oi){
    int obase = w*96 + oi*16;
    for(int nj = 0; nj < 4; ++nj){
      int n = n0 + nj*16 + lo;
      if(obase < 128){
        short4_t pk;
        #pragma unroll
        for(int r = 0; r < 4; ++r) pk[r] = f2bf(acc[oi][nj][r]);
        *(short4_t*)(&qk[((size_t)b*N_ + n)*128 + obase + 4*g]) = pk;
      } else {
        float iv = inv[b*N_ + n];
        #pragma unroll
        for(int r = 0; r < 4; ++r){
          int o = obase + 4*g + r;
          vT[((size_t)b*C_ + (o-128))*N_ + n] = f2bf(acc[oi][nj][r]*iv);
        }
      }
    }
  }
}

// ---------------- K4: attention, single-pass, double-buffered LDS, ONE raw s_barrier
// per iter (lgkmcnt-only wait: global K/V prefetch stays in flight across it).
// block = 64 rows (4 waves x 16 rows QK^T; PV repartitioned wave->64 columns).
__global__ __launch_bounds__(256,2) void k_attn(const short* __restrict__ qk,
                                                const short* __restrict__ vT,
                                                short* __restrict__ att){
  int d = blockIdx.x;                  // 512 blocks; wg->XCD assumed d%8
  int xcd = d & 7, j = d >> 3;         // j: 0..63
  int b = xcd*2 + (j >> 5);            // 2 batches per XCD (L2 locality)
  int n0 = (j & 31)*64;
  int tid = threadIdx.x;
  int w = tid>>6, l = tid&63, lo = l&15, g = l>>4;

  __shared__ short vt_lds[2][C_][40];  // [buf][c'][32 m], 80B rows
  __shared__ short p_lds[2][64][40];   // [buf][n][m]
  __shared__ float rs_lds[64];

  const short* qkb = qk + (size_t)b*N_*128;
  const short* vtb = vT + (size_t)b*C_*N_;

  // Q fragment (B-operand of swapped QK^T): wave's 16 rows, n = n0 + w*16 + lo
  const short* qrow = qkb + (size_t)(n0 + w*16 + lo)*128;
  bf16x8 qa0 = *(const bf16x8*)(qrow + 8*g);
  bf16x8 qa1 = *(const bf16x8*)(qrow + 32 + 8*g);

  f32x4 oacc[4][4];                    // [rt rows][jj cols], cols = w*64..w*64+63
  #pragma unroll
  for(int rt=0;rt<4;++rt) for(int jj=0;jj<4;++jj) oacc[rt][jj]=(f32x4){0.f,0.f,0.f,0.f};
  float srow = 0.f;                    // row-sum for n = w*16 + lo (partial over g)

  int cp = tid>>2, ii = tid&3;         // V staging: row cp+64k, 16B at m0+8*ii

  // -- prologue: load K[0], V[0] into regs
  bf16x8 kb[2][2], vstg[4];
  #pragma unroll
  for(int tau = 0; tau < 2; ++tau){
    const short* kr = qkb + (size_t)(tau*16 + lo)*128 + 64;
    kb[tau][0] = *(const bf16x8*)(kr + 8*g);
    kb[tau][1] = *(const bf16x8*)(kr + 32 + 8*g);
  }
  #pragma unroll
  for(int kk = 0; kk < 4; ++kk)
    vstg[kk] = *(const bf16x8*)(vtb + (size_t)(cp + 64*kk)*N_ + 8*ii);

  #pragma unroll 1
  for(int mc = 0; mc < N_/32; ++mc){
    int buf = mc & 1;
    // -- QK^T swapped from regs: D[m on regs 4g+r][n on lanes lo]
    short4_t pk[2];
    #pragma unroll
    for(int tau = 0; tau < 2; ++tau){
      f32x4 a = (f32x4){0.f,0.f,0.f,0.f};
      a = __builtin_amdgcn_mfma_f32_16x16x32_bf16(kb[tau][0], qa0, a, 0,0,0);
      a = __builtin_amdgcn_mfma_f32_16x16x32_bf16(kb[tau][1], qa1, a, 0,0,0);
      #pragma unroll
      for(int r = 0; r < 4; ++r){
        float pe = __expf(a[r] - 12.f);
        srow += pe;
        pk[tau][r] = f2bf(pe);
      }
    }
    // -- ds_writes: p + V into buf
    #pragma unroll
    for(int tau = 0; tau < 2; ++tau)
      *(short4_t*)(&p_lds[buf][w*16 + lo][tau*16 + 4*g]) = pk[tau];
    #pragma unroll
    for(int kk = 0; kk < 4; ++kk)
      *(bf16x8*)(&vt_lds[buf][cp + 64*kk][8*ii]) = vstg[kk];
    // -- issue next-iter global loads (stay in flight across the barrier)
    int mnn = ((mc + 1) & (N_/32 - 1))*32;
    #pragma unroll
    for(int tau = 0; tau < 2; ++tau){
      const short* kr = qkb + (size_t)(mnn + tau*16 + lo)*128 + 64;
      kb[tau][0] = *(const bf16x8*)(kr + 8*g);
      kb[tau][1] = *(const bf16x8*)(kr + 32 + 8*g);
    }
    #pragma unroll
    for(int kk = 0; kk < 4; ++kk)
      vstg[kk] = *(const bf16x8*)(vtb + (size_t)(cp + 64*kk)*N_ + mnn + 8*ii);
    // -- lgkm-only drain + raw barrier (NO vmcnt drain)
    __builtin_amdgcn_sched_barrier(0);
    asm volatile("s_waitcnt lgkmcnt(0)" ::: "memory");
    __builtin_amdgcn_s_barrier();
    __builtin_amdgcn_sched_barrier(0);
    // -- PV: wave computes all 64 rows x its 64 cols (8 LDS reads, 16 MFMAs)
    bf16x8 pa[4], bv[4];
    #pragma unroll
    for(int rt = 0; rt < 4; ++rt) pa[rt] = *(const bf16x8*)(&p_lds[buf][rt*16 + lo][8*g]);
    #pragma unroll
    for(int jj = 0; jj < 4; ++jj) bv[jj] = *(const bf16x8*)(&vt_lds[buf][(w*4+jj)*16 + lo][8*g]);
    #pragma unroll
    for(int rt = 0; rt < 4; ++rt)
      #pragma unroll
      for(int jj = 0; jj < 4; ++jj)
        oacc[rt][jj] = __builtin_amdgcn_mfma_f32_16x16x32_bf16(pa[rt], bv[jj], oacc[rt][jj], 0,0,0);
  }

  // -- finalize row sums: combine g-groups, share across waves via LDS
  float S = srow;
  S += __shfl_xor(S, 16);
  S += __shfl_xor(S, 32);
  if(l < 16) rs_lds[w*16 + l] = 1.f/(S + 1e-30f);
  __syncthreads();
  float rinvs[4][4];
  #pragma unroll
  for(int rt = 0; rt < 4; ++rt)
    #pragma unroll
    for(int r = 0; r < 4; ++r) rinvs[rt][r] = rs_lds[rt*16 + 4*g + r];

  short* attb = att + (size_t)b*N_*C_;
  #pragma unroll
  for(int rt = 0; rt < 4; ++rt)
    #pragma unroll
    for(int jj = 0; jj < 4; ++jj)
      #pragma unroll
      for(int r = 0; r < 4; ++r){
        int n = n0 + rt*16 + 4*g + r;
        int c = w*64 + jj*16 + lo;
        attb[(size_t)n*C_ + c] = f2bf(oacc[rt][jj][r]*rinvs[rt][r]);
      }
}

// ---------------- K5: h[b][n][o] = sum_c Wl[o,c]*(x[c,n]-att[n,c]); BN partial sums
__global__ __launch_bounds__(256,2) void k_hgemm(const float* __restrict__ x,
        const short* __restrict__ att, const short* __restrict__ Wlb,
        short* __restrict__ h, float* __restrict__ bnsum, float* __restrict__ bnssq){
  int b = blockIdx.y; int n0 = blockIdx.x*64;
  int tid = threadIdx.x, w = tid>>6, l = tid&63, lo = l&15, g = l>>4;
  __shared__ short rT[64][40];
  const float* xb = x + (size_t)b*C_*N_;
  const short* attb = att + (size_t)b*N_*C_;
  f32x4 acc[4][4];
  #pragma unroll
  for(int ot=0;ot<4;++ot) for(int nj=0;nj<4;++nj) acc[ot][nj]=(f32x4){0.f,0.f,0.f,0.f};
  for(int cc = 0; cc < C_; cc += 32){
    __syncthreads();
    #pragma unroll
    for(int kk = 0; kk < 4; ++kk){
      int pp = w + 4*kk;
      int ci = cc + 2*pp;
      float a  = xb[(size_t)ci*N_ + n0 + l];
      float c2 = xb[(size_t)(ci+1)*N_ + n0 + l];
      unsigned pr = (unsigned)(unsigned short)f2bf(a) | (((unsigned)(unsigned short)f2bf(c2))<<16);
      *(unsigned*)(&rT[l][2*pp]) = pr;
    }
    __syncthreads();
    {   // r = x - att (LDS RMW, b128)
      int n = tid>>2, ii = tid&3;
      bf16x8 av = *(const bf16x8*)(attb + (size_t)(n0+n)*C_ + cc + 8*ii);
      bf16x8* pr = (bf16x8*)(&rT[n][8*ii]);
      bf16x8 xv = *pr, rv;
      #pragma unroll
      for(int j = 0; j < 8; ++j) rv[j] = f2bf(bf2f(xv[j]) - bf2f(av[j]));
      *pr = rv;
    }
    __syncthreads();
    bf16x8 bfr[4];
    #pragma unroll
    for(int nj = 0; nj < 4; ++nj) bfr[nj] = *(const bf16x8*)(&rT[nj*16 + lo][8*g]);
    #pragma unroll
    for(int ot = 0; ot < 4; ++ot){
      int o = w*64 + ot*16 + lo;
      bf16x8 af = *(const bf16x8*)(Wlb + (size_t)o*C_ + cc + 8*g);
      #pragma unroll
      for(int nj = 0; nj < 4; ++nj)
        acc[ot][nj] = __builtin_amdgcn_mfma_f32_16x16x32_bf16(af, bfr[nj], acc[ot][nj], 0,0,0);
    }
  }
  short* hb = h + (size_t)b*N_*C_;
  #pragma unroll
  for(int ot = 0; ot < 4; ++ot)
    for(int nj = 0; nj < 4; ++nj){
      int n = n0 + nj*16 + lo;
      short4_t pk;
      #pragma unroll
      for(int r = 0; r < 4; ++r) pk[r] = f2bf(acc[ot][nj][r]);
      *(short4_t*)(&hb[(size_t)n*C_ + w*64 + ot*16 + 4*g]) = pk;
    }
  #pragma unroll
  for(int ot = 0; ot < 4; ++ot){
    float s4[4] = {0,0,0,0}, q4[4] = {0,0,0,0};
    for(int nj = 0; nj < 4; ++nj)
      #pragma unroll
      for(int r = 0; r < 4; ++r){ float v = acc[ot][nj][r]; s4[r] += v; q4[r] += v*v; }
    #pragma unroll
    for(int r = 0; r < 4; ++r){
      float ss = s4[r], qq = q4[r];
      for(int msk = 1; msk < 16; msk <<= 1){ ss += __shfl_xor(ss, msk); qq += __shfl_xor(qq, msk); }
      if(lo == 0){
        int o = w*64 + ot*16 + 4*g + r;
        atomicAdd(&bnsum[o], ss);
        atomicAdd(&bnssq[o], qq);
      }
    }
  }
}

// ---------------- K6: BN finalize -> scale/shift per channel
__global__ void k_bnfin(const float* __restrict__ bnsum, const float* __restrict__ bnssq,
                        const float* __restrict__ gamma, const float* __restrict__ beta,
                        float* __restrict__ bnsc, float* __restrict__ bnsh){
  int o = threadIdx.x;
  float cnt = (float)(B_*N_);
  float mean = bnsum[o]/cnt;
  float var  = bnssq[o]/cnt - mean*mean;
  float is   = rsqrtf(var + 1e-5f);
  float sc   = gamma[o]*is;
  bnsc[o] = sc;
  bnsh[o] = beta[o] - mean*sc;
}

// ---------------- K7: out[c][n] = x + relu(h*sc+sh)  (LDS transpose of h[n][o])
__global__ void k_final(const float* __restrict__ x, const short* __restrict__ h,
                        const float* __restrict__ bnsc, const float* __restrict__ bnsh,
                        float* __restrict__ out){
  int b = blockIdx.z, c0 = blockIdx.y*64, n0 = blockIdx.x*64;
  int tid = threadIdx.x;
  __shared__ float ht[64][65];
  {
    int n = tid>>2, ii = tid&3;
    #pragma unroll
    for(int p = 0; p < 2; ++p){
      int coff = 32*p + 8*ii;
      bf16x8 hv = *(const bf16x8*)(h + ((size_t)(b*N_ + n0 + n))*C_ + c0 + coff);
      #pragma unroll
      for(int j = 0; j < 8; ++j) ht[n][coff + j] = bf2f(hv[j]);
    }
  }
  __syncthreads();
  int c = tid>>2, i2 = tid&3;
  float sc = bnsc[c0 + c], sh = bnsh[c0 + c];
  const float* xr = x + ((size_t)b*C_ + c0 + c)*N_ + n0 + 16*i2;
  float* orow = out + ((size_t)b*C_ + c0 + c)*N_ + n0 + 16*i2;
  #pragma unroll
  for(int k = 0; k < 16; k += 4){
    f32x4 xv = *(const f32x4*)(xr + k);
    f32x4 ov;
    #pragma unroll
    for(int j = 0; j < 4; ++j){
      float bn = ht[16*i2 + k + j][c]*sc + sh;
      ov[j] = xv[j] + fmaxf(bn, 0.f);
    }
    *(f32x4*)(orow + k) = ov;
  }
}

extern "C" void kernel_launch(void* const* d_in, const int* in_sizes, int n_in,
                              void* d_out, int out_size, void* d_ws, size_t ws_size,
                              hipStream_t stream){
  const float* x     = (const float*)d_in[0];
  const float* Wq    = (const float*)d_in[1];
  const float* Wk    = (const float*)d_in[2];
  const float* Wv    = (const float*)d_in[3];
  const float* Wl    = (const float*)d_in[4];
  const float* gamma = (const float*)d_in[5];
  const float* beta  = (const float*)d_in[6];
  float* out = (float*)d_out;

  char* p = (char*)d_ws;
  double* g    = (double*)p; p += (size_t)B_*C_*8;
  double* xsum = (double*)p; p += (size_t)B_*C_*8;
  float* inv  = (float*)p;  p += (size_t)B_*N_*4;
  short* Wb   = (short*)p;  p += (size_t)384*C_*2;
  short* Wlb  = (short*)p;  p += (size_t)C_*C_*2;
  short* qk   = (short*)p;  p += (size_t)B_*N_*128*2;
  short* vT   = (short*)p;  p += (size_t)B_*C_*N_*2;
  short* att  = (short*)p;  p += (size_t)B_*N_*C_*2;
  short* h    = (short*)p;  p += (size_t)B_*N_*C_*2;
  float* bnsum= (float*)p;  p += C_*4;
  float* bnssq= (float*)p;  p += C_*4;
  float* bnsc = (float*)p;  p += C_*4;
  float* bnsh = (float*)p;  p += C_*4;

  hipMemsetAsync(bnsum, 0, 2*C_*sizeof(float), stream);

  k_convw  <<<384, 256, 0, stream>>>(Wq, Wk, Wv, Wl, Wb, Wlb);
  k_xsum   <<<dim3(C_/4, B_), 256, 0, stream>>>(x, xsum);
  k_prep_g2<<<B_, 256, 0, stream>>>(xsum, Wq, Wk, g);
  k_colsum <<<dim3(N_/128, B_), 256, 0, stream>>>(x, g, inv);
  k_qkv    <<<dim3(N_/64, B_), 256, 0, stream>>>(x, Wb, inv, qk, vT);
  k_attn   <<<512, 256, 0, stream>>>(qk, vT, att);
  k_hgemm  <<<dim3(N_/64, B_), 256, 0, stream>>>(x, att, Wlb, h, bnsum, bnssq);
  k_bnfin  <<<1, 256, 0, stream>>>(bnsum, bnssq, gamma, beta, bnsc, bnsh);
  k_final  <<<dim3(N_/64, C_/64, B_), 256, 0, stream>>>(x, h, bnsc, bnsh, out);
}

// Round 8
// 204.053 us; speedup vs baseline: 2.2122x; 1.1841x over previous
//
#include <hip/hip_runtime.h>

#define B_ 16
#define C_ 256
#define N_ 2048
#define CK_ 64

using f32x4  = __attribute__((ext_vector_type(4))) float;
using bf16x8 = __attribute__((ext_vector_type(8))) short;
using short4_t = __attribute__((ext_vector_type(4))) short;

static __device__ __forceinline__ float bf2f(short s){
  unsigned u = ((unsigned)(unsigned short)s) << 16;
  float f; __builtin_memcpy(&f, &u, 4); return f;
}
static __device__ __forceinline__ short f2bf(float f){
  unsigned u; __builtin_memcpy(&u, &f, 4);
  unsigned r = (u + 0x7fffu + ((u >> 16) & 1u)) >> 16;   // RNE
  return (short)(unsigned short)r;
}

// XOR-swizzled byte offsets (128B pair-rows): bank-conflict-minimal for both
// the b128 fragment reads and the linear global_load_lds staging.
static __device__ __forceinline__ int vf_off(int cp, int ck){   // cp 0..255, ck 0..3 -> within 16KB
  int q = cp >> 1; int ch = (((cp & 1) << 2) | ck) ^ (q & 7);
  return q*128 + ch*16;
}
static __device__ __forceinline__ int p_off(int n, int ck){     // n 0..63, ck 0..3 -> within 8KB
  int q = n >> 1; int ch = (((n & 1) << 2) | ck) ^ (q & 7);
  return q*128 + ch*16;
}

// ---------------- K0: weights -> bf16 (Wb rows: [0,64)=Wq, [64,128)=Wk, [128,384)=Wv)
__global__ void k_convw(const float* __restrict__ Wq, const float* __restrict__ Wk,
                        const float* __restrict__ Wv, const float* __restrict__ Wl,
                        short* __restrict__ Wb, short* __restrict__ Wlb){
  int i = blockIdx.x*256 + threadIdx.x;
  if(i < 384*C_){
    int o = i >> 8;
    float v;
    if(o < 64)       v = Wq[i];
    else if(o < 128) v = Wk[i - 64*C_];
    else             v = Wv[i - 128*C_];
    Wb[i] = f2bf(v);
  }
  if(i < C_*C_) Wlb[i] = f2bf(Wl[i]);
}

// ---------------- K1a: xsum[b,c] = sum_n x[b,c,n]  (f64, wave-per-row)
__global__ void k_xsum(const float* __restrict__ x, double* __restrict__ xsum){
  int b = blockIdx.y;
  int c = blockIdx.x*4 + (threadIdx.x>>6);
  int l = threadIdx.x & 63;
  const float* row = x + ((size_t)b*C_ + c)*N_;
  double s = 0.0;
  #pragma unroll
  for(int it = 0; it < 8; ++it){
    f32x4 v = *(const f32x4*)(row + it*256 + l*4);
    s += (double)v[0] + (double)v[1] + (double)v[2] + (double)v[3];
  }
  for(int off = 32; off; off >>= 1) s += __shfl_down(s, off);
  if(l == 0) xsum[b*C_ + c] = s;
}

// ---------------- K1b: g[b,:] = Wk^T (Wq xsum)   (f64 exact colsum prep, tiny)
__global__ void k_prep_g2(const double* __restrict__ xsum, const float* __restrict__ Wq,
                          const float* __restrict__ Wk, double* __restrict__ g){
  int b = blockIdx.x;
  __shared__ double xs[C_];
  __shared__ double t[CK_];
  int tid = threadIdx.x;
  xs[tid] = xsum[b*C_ + tid];
  __syncthreads();
  if(tid < CK_){
    double s = 0.0;
    const float* wr = Wq + (size_t)tid*C_;
    for(int c = 0; c < C_; ++c) s += (double)wr[c]*xs[c];
    t[tid] = s;
  }
  __syncthreads();
  double s = 0.0;
  for(int j = 0; j < CK_; ++j) s += (double)Wk[(size_t)j*C_ + tid]*t[j];
  g[b*C_ + tid] = s;
}

// ---------------- K3: QKV projection. Outputs:
//   qbuf[b][n][64]          (128B rows, coalesced fragment reads)
//   kf[b][mt][h][64][8]     (exact MFMA A-fragment order -> 1KB coalesced loads)
//   vf[b][mc][swizzled 16KB] (pre-swizzled for linear global_load_lds staging)
// colsum fused in f64: inv[n] = 1/(1e-9 + sum_c g[c] x[c,n]) applied to V.
__global__ __launch_bounds__(256,2) void k_qkv(const float* __restrict__ x,
        const short* __restrict__ Wb, const double* __restrict__ gg,
        short* __restrict__ qbuf, short* __restrict__ kf, short* __restrict__ vf){
  int b = blockIdx.y; int n0 = blockIdx.x*64;
  int tid = threadIdx.x, w = tid>>6, l = tid&63, lo = l&15, g = l>>4;
  __shared__ short xT[64][40];                 // [n][c-chunk], 80B rows
  __shared__ double gs[C_];
  __shared__ double csum[4][64];
  __shared__ float inv_lds[64];
  const float* xb = x + (size_t)b*C_*N_;
  gs[tid] = gg[b*C_ + tid];
  f32x4 acc[6][4];
  #pragma unroll
  for(int oi=0;oi<6;++oi) for(int nj=0;nj<4;++nj) acc[oi][nj]=(f32x4){0.f,0.f,0.f,0.f};
  double cs = 0.0;
  for(int cc = 0; cc < C_; cc += 32){
    __syncthreads();
    #pragma unroll
    for(int kk = 0; kk < 4; ++kk){             // stage x^T (pair-packed b32 writes)
      int pp = w + 4*kk;
      int ci = cc + 2*pp;
      float a  = xb[(size_t)ci*N_ + n0 + l];
      float c2 = xb[(size_t)(ci+1)*N_ + n0 + l];
      cs += (double)a*gs[ci] + (double)c2*gs[ci+1];
      unsigned pr = (unsigned)(unsigned short)f2bf(a) | (((unsigned)(unsigned short)f2bf(c2))<<16);
      *(unsigned*)(&xT[l][2*pp]) = pr;
    }
    __syncthreads();
    bf16x8 bfr[4];
    #pragma unroll
    for(int nj = 0; nj < 4; ++nj) bfr[nj] = *(const bf16x8*)(&xT[nj*16 + lo][8*g]);
    #pragma unroll
    for(int oi = 0; oi < 6; ++oi){
      int o = w*96 + oi*16 + lo;
      bf16x8 af = *(const bf16x8*)(Wb + (size_t)o*C_ + cc + 8*g);
      #pragma unroll
      for(int nj = 0; nj < 4; ++nj)
        acc[oi][nj] = __builtin_amdgcn_mfma_f32_16x16x32_bf16(af, bfr[nj], acc[oi][nj], 0,0,0);
    }
  }
  __syncthreads();
  csum[w][l] = cs;
  __syncthreads();
  if(tid < 64){
    double t = csum[0][tid] + csum[1][tid] + csum[2][tid] + csum[3][tid];
    inv_lds[tid] = (float)(1.0/(1e-9 + t));
  }
  __syncthreads();

  short* qb  = qbuf + (size_t)b*N_*64;
  short* kfb = kf   + (size_t)b*N_*64;
  short* vfb = vf   + (size_t)b*C_*N_;
  #pragma unroll
  for(int oi = 0; oi < 6; ++oi){
    int obase = w*96 + oi*16;
    for(int nj = 0; nj < 4; ++nj){
      int n = n0 + nj*16 + lo;
      if(obase < 64){                          // Q rows
        short4_t pk;
        #pragma unroll
        for(int r = 0; r < 4; ++r) pk[r] = f2bf(acc[oi][nj][r]);
        *(short4_t*)(qb + (size_t)n*64 + obase + 4*g) = pk;
      } else if(obase < 128){                  // K fragments
        int C0 = obase - 64 + 4*g;
        int mt = (n0>>4) + nj;
        int h  = C0 >> 5;
        int lanep = ((C0>>3)&3)*16 + lo;
        short4_t pk;
        #pragma unroll
        for(int r = 0; r < 4; ++r) pk[r] = f2bf(acc[oi][nj][r]);
        *(short4_t*)(kfb + ((size_t)(mt*2 + h)*64 + lanep)*8 + (C0&4)) = pk;
      } else {                                 // V pre-swizzled
        float iv = inv_lds[nj*16 + lo];
        int ckk = (n>>3)&3, wi = n&7, mc = n>>5;
        #pragma unroll
        for(int r = 0; r < 4; ++r){
          int cp = obase - 128 + 4*g + r;
          vfb[(size_t)mc*8192 + (vf_off(cp, ckk)>>1) + wi] = f2bf(acc[oi][nj][r]*iv);
        }
      }
    }
  }
}

// ---------------- K4: attention. Single-pass no-max softmax, swapped QK^T,
// double-buffered swizzled LDS, global_load_lds V staging, one barrier/iter
// with counted vmcnt(8) (V-DMA stays in flight across the barrier).
__global__ __launch_bounds__(256,2) void k_attn(const short* __restrict__ qbuf,
        const short* __restrict__ kf, const short* __restrict__ vf,
        short* __restrict__ att){
  int d = blockIdx.x;                  // 512 blocks; wg->XCD assumed d%8
  int xcd = d & 7, j = d >> 3;
  int b = xcd*2 + (j >> 5);            // 2 batches per XCD
  int n0 = (j & 31)*64;
  int tid = threadIdx.x;
  int w = tid>>6, l = tid&63, lo = l&15, g = l>>4;

  __shared__ short vlds[2][8192];      // 2 x 16KB swizzled V chunk
  __shared__ short plds[2][4096];      // 2 x 8KB swizzled p tile
  __shared__ float rs_lds[64];

  const short* qb  = qbuf + (size_t)b*N_*64;
  const short* kfb = kf   + (size_t)b*N_*64;
  const short* vfb = vf   + (size_t)b*C_*N_;

  // Q fragments (coalesced 2KB window)
  bf16x8 qa0, qa1;
  {
    const short* qrow = qb + (size_t)(n0 + w*16 + lo)*64;
    qa0 = *(const bf16x8*)(qrow + 8*g);
    qa1 = *(const bf16x8*)(qrow + 32 + 8*g);
  }
  // loop-invariant LDS byte offsets
  int paoff[4], bvoff[4];
  #pragma unroll
  for(int rt = 0; rt < 4; ++rt) paoff[rt] = p_off(rt*16 + lo, g);
  #pragma unroll
  for(int jj = 0; jj < 4; ++jj) bvoff[jj] = vf_off(w*64 + jj*16 + lo, g);
  int pw0 = p_off(w*16 + lo, (g>>1))     + (g&1)*8;   // tau=0
  int pw1 = p_off(w*16 + lo, 2 + (g>>1)) + (g&1)*8;   // tau=1

  const short* kl   = kfb + l*8;       // K lane base (fragment-major)
  const short* vsrc = vfb + w*2048 + l*8;

  f32x4 oacc[4][4];
  #pragma unroll
  for(int rt=0;rt<4;++rt) for(int jj=0;jj<4;++jj) oacc[rt][jj]=(f32x4){0.f,0.f,0.f,0.f};
  float srow = 0.f;

  bf16x8 kb00, kb01, kb10, kb11;

#define LOADK(MC) { const short* kp = kl + (size_t)(MC)*2048; \
    kb00 = *(const bf16x8*)(kp);        kb01 = *(const bf16x8*)(kp + 512); \
    kb10 = *(const bf16x8*)(kp + 1024); kb11 = *(const bf16x8*)(kp + 1536); }
#define GLLDS(SRC, DST) __builtin_amdgcn_global_load_lds( \
    (const __attribute__((address_space(1))) void*)(SRC), \
    (__attribute__((address_space(3))) void*)(DST), 16, 0, 0)
#define VDMA(MC, NB) { const short* vs = vsrc + (size_t)(MC)*8192; \
    GLLDS(vs,        (char*)&vlds[NB][0] + w*4096);        \
    GLLDS(vs +  512, (char*)&vlds[NB][0] + w*4096 + 1024); \
    GLLDS(vs + 1024, (char*)&vlds[NB][0] + w*4096 + 2048); \
    GLLDS(vs + 1536, (char*)&vlds[NB][0] + w*4096 + 3072); }

  // prologue: K(0) regs, V(0) -> buf0
  LOADK(0);
  VDMA(0, 0);

#define BODY(BUF, MC) { \
    f32x4 a0 = (f32x4){0.f,0.f,0.f,0.f}, a1 = (f32x4){0.f,0.f,0.f,0.f}; \
    a0 = __builtin_amdgcn_mfma_f32_16x16x32_bf16(kb00, qa0, a0, 0,0,0); \
    a0 = __builtin_amdgcn_mfma_f32_16x16x32_bf16(kb01, qa1, a0, 0,0,0); \
    a1 = __builtin_amdgcn_mfma_f32_16x16x32_bf16(kb10, qa0, a1, 0,0,0); \
    a1 = __builtin_amdgcn_mfma_f32_16x16x32_bf16(kb11, qa1, a1, 0,0,0); \
    short4_t pk0, pk1; \
    _Pragma("unroll") \
    for(int r = 0; r < 4; ++r){ \
      float e0 = __builtin_exp2f(fmaf(a0[r], 1.44269504f, -17.3123405f)); \
      float e1 = __builtin_exp2f(fmaf(a1[r], 1.44269504f, -17.3123405f)); \
      srow += e0 + e1; pk0[r] = f2bf(e0); pk1[r] = f2bf(e1); } \
    *(short4_t*)((char*)&plds[BUF][0] + pw0) = pk0; \
    *(short4_t*)((char*)&plds[BUF][0] + pw1) = pk1; \
    { int mn = ((MC) + 1) & 63; \
      LOADK(mn); \
      VDMA(mn, (BUF)^1); } \
    __builtin_amdgcn_sched_barrier(0); \
    asm volatile("s_waitcnt vmcnt(8) lgkmcnt(0)" ::: "memory"); \
    __builtin_amdgcn_s_barrier(); \
    __builtin_amdgcn_sched_barrier(0); \
    bf16x8 pa[4], bv[4]; \
    _Pragma("unroll") \
    for(int rt = 0; rt < 4; ++rt) pa[rt] = *(const bf16x8*)((char*)&plds[BUF][0] + paoff[rt]); \
    _Pragma("unroll") \
    for(int jj = 0; jj < 4; ++jj) bv[jj] = *(const bf16x8*)((char*)&vlds[BUF][0] + bvoff[jj]); \
    _Pragma("unroll") \
    for(int rt = 0; rt < 4; ++rt) \
      _Pragma("unroll") \
      for(int jj = 0; jj < 4; ++jj) \
        oacc[rt][jj] = __builtin_amdgcn_mfma_f32_16x16x32_bf16(pa[rt], bv[jj], oacc[rt][jj], 0,0,0); }

  #pragma unroll 1
  for(int it = 0; it < 32; ++it){
    BODY(0, 2*it);
    BODY(1, 2*it + 1);
  }
#undef BODY
#undef VDMA
#undef GLLDS
#undef LOADK

  // row-sum completion
  float S = srow;
  S += __shfl_xor(S, 16);
  S += __shfl_xor(S, 32);
  if(l < 16) rs_lds[w*16 + l] = 1.f/(S + 1e-30f);
  __syncthreads();
  float rinvs[4][4];
  #pragma unroll
  for(int rt = 0; rt < 4; ++rt)
    #pragma unroll
    for(int r = 0; r < 4; ++r) rinvs[rt][r] = rs_lds[rt*16 + 4*g + r];

  short* attb = att + (size_t)b*N_*C_;
  #pragma unroll
  for(int rt = 0; rt < 4; ++rt)
    #pragma unroll
    for(int jj = 0; jj < 4; ++jj)
      #pragma unroll
      for(int r = 0; r < 4; ++r){
        int n = n0 + rt*16 + 4*g + r;
        int c = w*64 + jj*16 + lo;
        attb[(size_t)n*C_ + c] = f2bf(oacc[rt][jj][r]*rinvs[rt][r]);
      }
}

// ---------------- K5: h[b][n][o] = sum_c Wl[o,c]*(x[c,n]-att[n,c]); BN partial sums
__global__ __launch_bounds__(256,2) void k_hgemm(const float* __restrict__ x,
        const short* __restrict__ att, const short* __restrict__ Wlb,
        short* __restrict__ h, float* __restrict__ bnsum, float* __restrict__ bnssq){
  int b = blockIdx.y; int n0 = blockIdx.x*64;
  int tid = threadIdx.x, w = tid>>6, l = tid&63, lo = l&15, g = l>>4;
  __shared__ short rT[64][40];
  const float* xb = x + (size_t)b*C_*N_;
  const short* attb = att + (size_t)b*N_*C_;
  f32x4 acc[4][4];
  #pragma unroll
  for(int ot=0;ot<4;++ot) for(int nj=0;nj<4;++nj) acc[ot][nj]=(f32x4){0.f,0.f,0.f,0.f};
  for(int cc = 0; cc < C_; cc += 32){
    __syncthreads();
    #pragma unroll
    for(int kk = 0; kk < 4; ++kk){
      int pp = w + 4*kk;
      int ci = cc + 2*pp;
      float a  = xb[(size_t)ci*N_ + n0 + l];
      float c2 = xb[(size_t)(ci+1)*N_ + n0 + l];
      unsigned pr = (unsigned)(unsigned short)f2bf(a) | (((unsigned)(unsigned short)f2bf(c2))<<16);
      *(unsigned*)(&rT[l][2*pp]) = pr;
    }
    __syncthreads();
    {   // r = x - att (LDS RMW, b128)
      int n = tid>>2, ii = tid&3;
      bf16x8 av = *(const bf16x8*)(attb + (size_t)(n0+n)*C_ + cc + 8*ii);
      bf16x8* pr = (bf16x8*)(&rT[n][8*ii]);
      bf16x8 xv = *pr, rv;
      #pragma unroll
      for(int jq = 0; jq < 8; ++jq) rv[jq] = f2bf(bf2f(xv[jq]) - bf2f(av[jq]));
      *pr = rv;
    }
    __syncthreads();
    bf16x8 bfr[4];
    #pragma unroll
    for(int nj = 0; nj < 4; ++nj) bfr[nj] = *(const bf16x8*)(&rT[nj*16 + lo][8*g]);
    #pragma unroll
    for(int ot = 0; ot < 4; ++ot){
      int o = w*64 + ot*16 + lo;
      bf16x8 af = *(const bf16x8*)(Wlb + (size_t)o*C_ + cc + 8*g);
      #pragma unroll
      for(int nj = 0; nj < 4; ++nj)
        acc[ot][nj] = __builtin_amdgcn_mfma_f32_16x16x32_bf16(af, bfr[nj], acc[ot][nj], 0,0,0);
    }
  }
  short* hb = h + (size_t)b*N_*C_;
  #pragma unroll
  for(int ot = 0; ot < 4; ++ot)
    for(int nj = 0; nj < 4; ++nj){
      int n = n0 + nj*16 + lo;
      short4_t pk;
      #pragma unroll
      for(int r = 0; r < 4; ++r) pk[r] = f2bf(acc[ot][nj][r]);
      *(short4_t*)(&hb[(size_t)n*C_ + w*64 + ot*16 + 4*g]) = pk;
    }
  #pragma unroll
  for(int ot = 0; ot < 4; ++ot){
    float s4[4] = {0,0,0,0}, q4[4] = {0,0,0,0};
    for(int nj = 0; nj < 4; ++nj)
      #pragma unroll
      for(int r = 0; r < 4; ++r){ float v = acc[ot][nj][r]; s4[r] += v; q4[r] += v*v; }
    #pragma unroll
    for(int r = 0; r < 4; ++r){
      float ss = s4[r], qq = q4[r];
      for(int msk = 1; msk < 16; msk <<= 1){ ss += __shfl_xor(ss, msk); qq += __shfl_xor(qq, msk); }
      if(lo == 0){
        int o = w*64 + ot*16 + 4*g + r;
        atomicAdd(&bnsum[o], ss);
        atomicAdd(&bnssq[o], qq);
      }
    }
  }
}

// ---------------- K6: BN finalize -> scale/shift per channel
__global__ void k_bnfin(const float* __restrict__ bnsum, const float* __restrict__ bnssq,
                        const float* __restrict__ gamma, const float* __restrict__ beta,
                        float* __restrict__ bnsc, float* __restrict__ bnsh){
  int o = threadIdx.x;
  float cnt = (float)(B_*N_);
  float mean = bnsum[o]/cnt;
  float var  = bnssq[o]/cnt - mean*mean;
  float is   = rsqrtf(var + 1e-5f);
  float sc   = gamma[o]*is;
  bnsc[o] = sc;
  bnsh[o] = beta[o] - mean*sc;
}

// ---------------- K7: out[c][n] = x + relu(h*sc+sh)  (LDS transpose of h[n][o])
__global__ void k_final(const float* __restrict__ x, const short* __restrict__ h,
                        const float* __restrict__ bnsc, const float* __restrict__ bnsh,
                        float* __restrict__ out){
  int b = blockIdx.z, c0 = blockIdx.y*64, n0 = blockIdx.x*64;
  int tid = threadIdx.x;
  __shared__ float ht[64][65];
  {
    int n = tid>>2, ii = tid&3;
    #pragma unroll
    for(int p = 0; p < 2; ++p){
      int coff = 32*p + 8*ii;
      bf16x8 hv = *(const bf16x8*)(h + ((size_t)(b*N_ + n0 + n))*C_ + c0 + coff);
      #pragma unroll
      for(int jq = 0; jq < 8; ++jq) ht[n][coff + jq] = bf2f(hv[jq]);
    }
  }
  __syncthreads();
  int c = tid>>2, i2 = tid&3;
  float sc = bnsc[c0 + c], sh = bnsh[c0 + c];
  const float* xr = x + ((size_t)b*C_ + c0 + c)*N_ + n0 + 16*i2;
  float* orow = out + ((size_t)b*C_ + c0 + c)*N_ + n0 + 16*i2;
  #pragma unroll
  for(int k = 0; k < 16; k += 4){
    f32x4 xv = *(const f32x4*)(xr + k);
    f32x4 ov;
    #pragma unroll
    for(int jq = 0; jq < 4; ++jq){
      float bn = ht[16*i2 + k + jq][c]*sc + sh;
      ov[jq] = xv[jq] + fmaxf(bn, 0.f);
    }
    *(f32x4*)(orow + k) = ov;
  }
}

extern "C" void kernel_launch(void* const* d_in, const int* in_sizes, int n_in,
                              void* d_out, int out_size, void* d_ws, size_t ws_size,
                              hipStream_t stream){
  const float* x     = (const float*)d_in[0];
  const float* Wq    = (const float*)d_in[1];
  const float* Wk    = (const float*)d_in[2];
  const float* Wv    = (const float*)d_in[3];
  const float* Wl    = (const float*)d_in[4];
  const float* gamma = (const float*)d_in[5];
  const float* beta  = (const float*)d_in[6];
  float* out = (float*)d_out;

  char* p = (char*)d_ws;
  double* g    = (double*)p; p += (size_t)B_*C_*8;
  double* xsum = (double*)p; p += (size_t)B_*C_*8;
  short* Wb   = (short*)p;  p += (size_t)384*C_*2;
  short* Wlb  = (short*)p;  p += (size_t)C_*C_*2;
  short* qbuf = (short*)p;  p += (size_t)B_*N_*64*2;
  short* kf   = (short*)p;  p += (size_t)B_*N_*64*2;
  short* vf   = (short*)p;  p += (size_t)B_*C_*N_*2;
  short* att  = (short*)p;  p += (size_t)B_*N_*C_*2;
  short* h    = (short*)p;  p += (size_t)B_*N_*C_*2;
  float* bnsum= (float*)p;  p += C_*4;
  float* bnssq= (float*)p;  p += C_*4;
  float* bnsc = (float*)p;  p += C_*4;
  float* bnsh = (float*)p;  p += C_*4;

  (void)hipMemsetAsync(bnsum, 0, 2*C_*sizeof(float), stream);

  k_convw  <<<384, 256, 0, stream>>>(Wq, Wk, Wv, Wl, Wb, Wlb);
  k_xsum   <<<dim3(C_/4, B_), 256, 0, stream>>>(x, xsum);
  k_prep_g2<<<B_, 256, 0, stream>>>(xsum, Wq, Wk, g);
  k_qkv    <<<dim3(N_/64, B_), 256, 0, stream>>>(x, Wb, g, qbuf, kf, vf);
  k_attn   <<<512, 256, 0, stream>>>(qbuf, kf, vf, att);
  k_hgemm  <<<dim3(N_/64, B_), 256, 0, stream>>>(x, att, Wlb, h, bnsum, bnssq);
  k_bnfin  <<<1, 256, 0, stream>>>(bnsum, bnssq, gamma, beta, bnsc, bnsh);
  k_final  <<<dim3(N_/64, C_/64, B_), 256, 0, stream>>>(x, h, bnsc, bnsh, out);
}

// Round 9
// 200.538 us; speedup vs baseline: 2.2510x; 1.0175x over previous
//
#include <hip/hip_runtime.h>

#define B_ 16
#define C_ 256
#define N_ 2048
#define CK_ 64

using f32x4  = __attribute__((ext_vector_type(4))) float;
using bf16x8 = __attribute__((ext_vector_type(8))) short;
using short4_t = __attribute__((ext_vector_type(4))) short;

static __device__ __forceinline__ float bf2f(short s){
  unsigned u = ((unsigned)(unsigned short)s) << 16;
  float f; __builtin_memcpy(&f, &u, 4); return f;
}
static __device__ __forceinline__ short f2bf(float f){
  unsigned u; __builtin_memcpy(&u, &f, 4);
  unsigned r = (u + 0x7fffu + ((u >> 16) & 1u)) >> 16;   // RNE
  return (short)(unsigned short)r;
}

// XOR-swizzled byte offsets (128B pair-rows) for k_attn's V/p LDS tiles.
static __device__ __forceinline__ int vf_off(int cp, int ck){   // cp 0..255, ck 0..3 -> within 16KB
  int q = cp >> 1; int ch = (((cp & 1) << 2) | ck) ^ (q & 7);
  return q*128 + ch*16;
}
static __device__ __forceinline__ int p_off(int n, int ck){     // n 0..63, ck 0..3 -> within 8KB
  int q = n >> 1; int ch = (((n & 1) << 2) | ck) ^ (q & 7);
  return q*128 + ch*16;
}

// ---------------- K0: weights -> bf16. Wb rows: [0,64)=Wq, [64,128)=Wk, [128,384)=Wv.
// Wlf: Wl in exact MFMA A-fragment order: Wlf[(c>>5)*8192 + (o>>4)*512 + l*8 + (c&7)],
// l = ((c>>3)&3)*16 + (o&15)  -> 1KB fully-coalesced fragment loads in k_hgemm.
__global__ void k_convw(const float* __restrict__ Wq, const float* __restrict__ Wk,
                        const float* __restrict__ Wv, const float* __restrict__ Wl,
                        short* __restrict__ Wb, short* __restrict__ Wlf){
  int i = blockIdx.x*256 + threadIdx.x;
  if(i < 384*C_){
    int o = i >> 8;
    float v;
    if(o < 64)       v = Wq[i];
    else if(o < 128) v = Wk[i - 64*C_];
    else             v = Wv[i - 128*C_];
    Wb[i] = f2bf(v);
  }
  if(i < C_*C_){
    int o = i >> 8, c = i & 255;
    int dest = (c>>5)*8192 + (o>>4)*512 + ((((c>>3)&3)*16) + (o&15))*8 + (c&7);
    Wlf[dest] = f2bf(Wl[i]);
  }
}

// ---------------- K1a: xsum[b,c] = sum_n x[b,c,n]  (f64, wave-per-row)
__global__ void k_xsum(const float* __restrict__ x, double* __restrict__ xsum){
  int b = blockIdx.y;
  int c = blockIdx.x*4 + (threadIdx.x>>6);
  int l = threadIdx.x & 63;
  const float* row = x + ((size_t)b*C_ + c)*N_;
  double s = 0.0;
  #pragma unroll
  for(int it = 0; it < 8; ++it){
    f32x4 v = *(const f32x4*)(row + it*256 + l*4);
    s += (double)v[0] + (double)v[1] + (double)v[2] + (double)v[3];
  }
  for(int off = 32; off; off >>= 1) s += __shfl_down(s, off);
  if(l == 0) xsum[b*C_ + c] = s;
}

// ---------------- K1b: g[b,:] = Wk^T (Wq xsum)   (f64 exact colsum prep, tiny)
__global__ void k_prep_g2(const double* __restrict__ xsum, const float* __restrict__ Wq,
                          const float* __restrict__ Wk, double* __restrict__ g){
  int b = blockIdx.x;
  __shared__ double xs[C_];
  __shared__ double t[CK_];
  int tid = threadIdx.x;
  xs[tid] = xsum[b*C_ + tid];
  __syncthreads();
  if(tid < CK_){
    double s = 0.0;
    const float* wr = Wq + (size_t)tid*C_;
    for(int c = 0; c < C_; ++c) s += (double)wr[c]*xs[c];
    t[tid] = s;
  }
  __syncthreads();
  double s = 0.0;
  for(int j = 0; j < CK_; ++j) s += (double)Wk[(size_t)j*C_ + tid]*t[j];
  g[b*C_ + tid] = s;
}

// ---------------- K3: QKV projection. Outputs:
//   qbuf[b][n][64], kf (fragment-major), vf (pre-swizzled), xTb[b][n][c] (bf16 x^T)
// colsum fused in f64: inv[n] = 1/(1e-9 + sum_c g[c] x[c,n]) applied to V.
__global__ __launch_bounds__(256,2) void k_qkv(const float* __restrict__ x,
        const short* __restrict__ Wb, const double* __restrict__ gg,
        short* __restrict__ qbuf, short* __restrict__ kf, short* __restrict__ vf,
        short* __restrict__ xTb){
  int b = blockIdx.y; int n0 = blockIdx.x*64;
  int tid = threadIdx.x, w = tid>>6, l = tid&63, lo = l&15, g = l>>4;
  __shared__ __attribute__((aligned(16))) short xT[64][40];   // [n][c-chunk], 80B rows
  __shared__ double gs[C_];
  __shared__ double csum[4][64];
  __shared__ float inv_lds[64];
  const float* xb = x + (size_t)b*C_*N_;
  gs[tid] = gg[b*C_ + tid];
  f32x4 acc[6][4];
  #pragma unroll
  for(int oi=0;oi<6;++oi) for(int nj=0;nj<4;++nj) acc[oi][nj]=(f32x4){0.f,0.f,0.f,0.f};
  double cs = 0.0;
  int n2 = tid>>2, ii2 = tid&3;
  short* xtb = xTb + ((size_t)b*N_ + n0)*C_;
  for(int cc = 0; cc < C_; cc += 32){
    __syncthreads();
    #pragma unroll
    for(int kk = 0; kk < 4; ++kk){             // stage x^T (pair-packed b32 writes)
      int pp = w + 4*kk;
      int ci = cc + 2*pp;
      float a  = xb[(size_t)ci*N_ + n0 + l];
      float c2 = xb[(size_t)(ci+1)*N_ + n0 + l];
      cs += (double)a*gs[ci] + (double)c2*gs[ci+1];
      unsigned pr = (unsigned)(unsigned short)f2bf(a) | (((unsigned)(unsigned short)f2bf(c2))<<16);
      *(unsigned*)(&xT[l][2*pp]) = pr;
    }
    __syncthreads();
    // write-back x^T bf16 to global (b128, 64B segments)
    *(bf16x8*)(xtb + (size_t)n2*C_ + cc + 8*ii2) = *(const bf16x8*)(&xT[n2][8*ii2]);
    bf16x8 bfr[4];
    #pragma unroll
    for(int nj = 0; nj < 4; ++nj) bfr[nj] = *(const bf16x8*)(&xT[nj*16 + lo][8*g]);
    #pragma unroll
    for(int oi = 0; oi < 6; ++oi){
      int o = w*96 + oi*16 + lo;
      bf16x8 af = *(const bf16x8*)(Wb + (size_t)o*C_ + cc + 8*g);
      #pragma unroll
      for(int nj = 0; nj < 4; ++nj)
        acc[oi][nj] = __builtin_amdgcn_mfma_f32_16x16x32_bf16(af, bfr[nj], acc[oi][nj], 0,0,0);
    }
  }
  __syncthreads();
  csum[w][l] = cs;
  __syncthreads();
  if(tid < 64){
    double t = csum[0][tid] + csum[1][tid] + csum[2][tid] + csum[3][tid];
    inv_lds[tid] = (float)(1.0/(1e-9 + t));
  }
  __syncthreads();

  short* qb  = qbuf + (size_t)b*N_*64;
  short* kfb = kf   + (size_t)b*N_*64;
  short* vfb = vf   + (size_t)b*C_*N_;
  #pragma unroll
  for(int oi = 0; oi < 6; ++oi){
    int obase = w*96 + oi*16;
    for(int nj = 0; nj < 4; ++nj){
      int n = n0 + nj*16 + lo;
      if(obase < 64){                          // Q rows
        short4_t pk;
        #pragma unroll
        for(int r = 0; r < 4; ++r) pk[r] = f2bf(acc[oi][nj][r]);
        *(short4_t*)(qb + (size_t)n*64 + obase + 4*g) = pk;
      } else if(obase < 128){                  // K fragments
        int C0 = obase - 64 + 4*g;
        int mt = (n0>>4) + nj;
        int h  = C0 >> 5;
        int lanep = ((C0>>3)&3)*16 + lo;
        short4_t pk;
        #pragma unroll
        for(int r = 0; r < 4; ++r) pk[r] = f2bf(acc[oi][nj][r]);
        *(short4_t*)(kfb + ((size_t)(mt*2 + h)*64 + lanep)*8 + (C0&4)) = pk;
      } else {                                 // V pre-swizzled
        float iv = inv_lds[nj*16 + lo];
        int ckk = (n>>3)&3, wi = n&7, mc = n>>5;
        #pragma unroll
        for(int r = 0; r < 4; ++r){
          int cp = obase - 128 + 4*g + r;
          vfb[(size_t)mc*8192 + (vf_off(cp, ckk)>>1) + wi] = f2bf(acc[oi][nj][r]*iv);
        }
      }
    }
  }
}

// ---------------- K4: attention (unchanged from round 8's passing version)
__global__ __launch_bounds__(256,2) void k_attn(const short* __restrict__ qbuf,
        const short* __restrict__ kf, const short* __restrict__ vf,
        short* __restrict__ att){
  int d = blockIdx.x;
  int xcd = d & 7, j = d >> 3;
  int b = xcd*2 + (j >> 5);
  int n0 = (j & 31)*64;
  int tid = threadIdx.x;
  int w = tid>>6, l = tid&63, lo = l&15, g = l>>4;

  __shared__ short vlds[2][8192];
  __shared__ short plds[2][4096];
  __shared__ float rs_lds[64];

  const short* qb  = qbuf + (size_t)b*N_*64;
  const short* kfb = kf   + (size_t)b*N_*64;
  const short* vfb = vf   + (size_t)b*C_*N_;

  bf16x8 qa0, qa1;
  {
    const short* qrow = qb + (size_t)(n0 + w*16 + lo)*64;
    qa0 = *(const bf16x8*)(qrow + 8*g);
    qa1 = *(const bf16x8*)(qrow + 32 + 8*g);
  }
  int paoff[4], bvoff[4];
  #pragma unroll
  for(int rt = 0; rt < 4; ++rt) paoff[rt] = p_off(rt*16 + lo, g);
  #pragma unroll
  for(int jj = 0; jj < 4; ++jj) bvoff[jj] = vf_off(w*64 + jj*16 + lo, g);
  int pw0 = p_off(w*16 + lo, (g>>1))     + (g&1)*8;
  int pw1 = p_off(w*16 + lo, 2 + (g>>1)) + (g&1)*8;

  const short* kl   = kfb + l*8;
  const short* vsrc = vfb + w*2048 + l*8;

  f32x4 oacc[4][4];
  #pragma unroll
  for(int rt=0;rt<4;++rt) for(int jj=0;jj<4;++jj) oacc[rt][jj]=(f32x4){0.f,0.f,0.f,0.f};
  float srow = 0.f;

  bf16x8 kb00, kb01, kb10, kb11;

#define LOADK(MC) { const short* kp = kl + (size_t)(MC)*2048; \
    kb00 = *(const bf16x8*)(kp);        kb01 = *(const bf16x8*)(kp + 512); \
    kb10 = *(const bf16x8*)(kp + 1024); kb11 = *(const bf16x8*)(kp + 1536); }
#define GLLDS(SRC, DST) __builtin_amdgcn_global_load_lds( \
    (const __attribute__((address_space(1))) void*)(SRC), \
    (__attribute__((address_space(3))) void*)(DST), 16, 0, 0)
#define VDMA(MC, NB) { const short* vs = vsrc + (size_t)(MC)*8192; \
    GLLDS(vs,        (char*)&vlds[NB][0] + w*4096);        \
    GLLDS(vs +  512, (char*)&vlds[NB][0] + w*4096 + 1024); \
    GLLDS(vs + 1024, (char*)&vlds[NB][0] + w*4096 + 2048); \
    GLLDS(vs + 1536, (char*)&vlds[NB][0] + w*4096 + 3072); }

  LOADK(0);
  VDMA(0, 0);

#define BODY(BUF, MC) { \
    f32x4 a0 = (f32x4){0.f,0.f,0.f,0.f}, a1 = (f32x4){0.f,0.f,0.f,0.f}; \
    a0 = __builtin_amdgcn_mfma_f32_16x16x32_bf16(kb00, qa0, a0, 0,0,0); \
    a0 = __builtin_amdgcn_mfma_f32_16x16x32_bf16(kb01, qa1, a0, 0,0,0); \
    a1 = __builtin_amdgcn_mfma_f32_16x16x32_bf16(kb10, qa0, a1, 0,0,0); \
    a1 = __builtin_amdgcn_mfma_f32_16x16x32_bf16(kb11, qa1, a1, 0,0,0); \
    short4_t pk0, pk1; \
    _Pragma("unroll") \
    for(int r = 0; r < 4; ++r){ \
      float e0 = __builtin_exp2f(fmaf(a0[r], 1.44269504f, -17.3123405f)); \
      float e1 = __builtin_exp2f(fmaf(a1[r], 1.44269504f, -17.3123405f)); \
      srow += e0 + e1; pk0[r] = f2bf(e0); pk1[r] = f2bf(e1); } \
    *(short4_t*)((char*)&plds[BUF][0] + pw0) = pk0; \
    *(short4_t*)((char*)&plds[BUF][0] + pw1) = pk1; \
    { int mn = ((MC) + 1) & 63; \
      LOADK(mn); \
      VDMA(mn, (BUF)^1); } \
    __builtin_amdgcn_sched_barrier(0); \
    asm volatile("s_waitcnt vmcnt(8) lgkmcnt(0)" ::: "memory"); \
    __builtin_amdgcn_s_barrier(); \
    __builtin_amdgcn_sched_barrier(0); \
    bf16x8 pa[4], bv[4]; \
    _Pragma("unroll") \
    for(int rt = 0; rt < 4; ++rt) pa[rt] = *(const bf16x8*)((char*)&plds[BUF][0] + paoff[rt]); \
    _Pragma("unroll") \
    for(int jj = 0; jj < 4; ++jj) bv[jj] = *(const bf16x8*)((char*)&vlds[BUF][0] + bvoff[jj]); \
    _Pragma("unroll") \
    for(int rt = 0; rt < 4; ++rt) \
      _Pragma("unroll") \
      for(int jj = 0; jj < 4; ++jj) \
        oacc[rt][jj] = __builtin_amdgcn_mfma_f32_16x16x32_bf16(pa[rt], bv[jj], oacc[rt][jj], 0,0,0); }

  #pragma unroll 1
  for(int it = 0; it < 32; ++it){
    BODY(0, 2*it);
    BODY(1, 2*it + 1);
  }
#undef BODY
#undef VDMA
#undef GLLDS
#undef LOADK

  float S = srow;
  S += __shfl_xor(S, 16);
  S += __shfl_xor(S, 32);
  if(l < 16) rs_lds[w*16 + l] = 1.f/(S + 1e-30f);
  __syncthreads();
  float rinvs[4][4];
  #pragma unroll
  for(int rt = 0; rt < 4; ++rt)
    #pragma unroll
    for(int r = 0; r < 4; ++r) rinvs[rt][r] = rs_lds[rt*16 + 4*g + r];

  short* attb = att + (size_t)b*N_*C_;
  #pragma unroll
  for(int rt = 0; rt < 4; ++rt)
    #pragma unroll
    for(int jj = 0; jj < 4; ++jj)
      #pragma unroll
      for(int r = 0; r < 4; ++r){
        int n = n0 + rt*16 + 4*g + r;
        int c = w*64 + jj*16 + lo;
        attb[(size_t)n*C_ + c] = f2bf(oacc[rt][jj][r]*rinvs[rt][r]);
      }
}

// ---------------- K5: h[n][o] = sum_c Wl[o,c]*(xT[n,c]-att[n,c]); BN partial sums.
// Load-once r-tile (coalesced b128), swizzled LDS, ONE barrier, fragment-major Wl.
__global__ __launch_bounds__(256,2) void k_hgemm(const short* __restrict__ xTb,
        const short* __restrict__ att, const short* __restrict__ Wlf,
        short* __restrict__ h, float* __restrict__ bnsum, float* __restrict__ bnssq){
  int b = blockIdx.y; int n0 = blockIdx.x*64;
  int tid = threadIdx.x, w = tid>>6, l = tid&63, lo = l&15, g = l>>4;
  __shared__ __attribute__((aligned(16))) short rT[64*C_];   // swizzled [n][ch^(n&7)]
  const short* xtb = xTb + ((size_t)b*N_ + n0)*C_;
  const short* atb = att + ((size_t)b*N_ + n0)*C_;
  int half = l >> 5, ch = l & 31;
  #pragma unroll
  for(int k = 0; k < 8; ++k){                  // 1KB fully-coalesced loads, 2 rows/instr
    int n = k*8 + w*2 + half;
    size_t off = (size_t)n*C_ + ch*8;
    bf16x8 xv = *(const bf16x8*)(xtb + off);
    bf16x8 av = *(const bf16x8*)(atb + off);
    bf16x8 rv;
    #pragma unroll
    for(int jq = 0; jq < 8; ++jq) rv[jq] = f2bf(bf2f(xv[jq]) - bf2f(av[jq]));
    *(bf16x8*)(&rT[n*C_ + ((ch ^ (n&7))*8)]) = rv;
  }
  __syncthreads();

  f32x4 acc[4][4];
  #pragma unroll
  for(int ot=0;ot<4;++ot) for(int nj=0;nj<4;++nj) acc[ot][nj]=(f32x4){0.f,0.f,0.f,0.f};
  #pragma unroll
  for(int cb = 0; cb < 8; ++cb){               // cc = cb*32, no barriers needed
    bf16x8 bfr[4];
    #pragma unroll
    for(int nj = 0; nj < 4; ++nj)
      bfr[nj] = *(const bf16x8*)(&rT[(nj*16 + lo)*C_ + (((cb*4 + g) ^ (lo&7))*8)]);
    #pragma unroll
    for(int ot = 0; ot < 4; ++ot){
      bf16x8 af = *(const bf16x8*)(Wlf + ((size_t)(cb*16 + w*4 + ot))*512 + l*8);
      #pragma unroll
      for(int nj = 0; nj < 4; ++nj)
        acc[ot][nj] = __builtin_amdgcn_mfma_f32_16x16x32_bf16(af, bfr[nj], acc[ot][nj], 0,0,0);
    }
  }
  short* hb = h + (size_t)b*N_*C_;
  #pragma unroll
  for(int ot = 0; ot < 4; ++ot)
    for(int nj = 0; nj < 4; ++nj){
      int n = n0 + nj*16 + lo;
      short4_t pk;
      #pragma unroll
      for(int r = 0; r < 4; ++r) pk[r] = f2bf(acc[ot][nj][r]);
      *(short4_t*)(&hb[(size_t)n*C_ + w*64 + ot*16 + 4*g]) = pk;
    }
  #pragma unroll
  for(int ot = 0; ot < 4; ++ot){
    float s4[4] = {0,0,0,0}, q4[4] = {0,0,0,0};
    for(int nj = 0; nj < 4; ++nj)
      #pragma unroll
      for(int r = 0; r < 4; ++r){ float v = acc[ot][nj][r]; s4[r] += v; q4[r] += v*v; }
    #pragma unroll
    for(int r = 0; r < 4; ++r){
      float ss = s4[r], qq = q4[r];
      for(int msk = 1; msk < 16; msk <<= 1){ ss += __shfl_xor(ss, msk); qq += __shfl_xor(qq, msk); }
      if(lo == 0){
        int o = w*64 + ot*16 + 4*g + r;
        atomicAdd(&bnsum[o], ss);
        atomicAdd(&bnssq[o], qq);
      }
    }
  }
}

// ---------------- K6: BN finalize -> scale/shift per channel
__global__ void k_bnfin(const float* __restrict__ bnsum, const float* __restrict__ bnssq,
                        const float* __restrict__ gamma, const float* __restrict__ beta,
                        float* __restrict__ bnsc, float* __restrict__ bnsh){
  int o = threadIdx.x;
  float cnt = (float)(B_*N_);
  float mean = bnsum[o]/cnt;
  float var  = bnssq[o]/cnt - mean*mean;
  float is   = rsqrtf(var + 1e-5f);
  float sc   = gamma[o]*is;
  bnsc[o] = sc;
  bnsh[o] = beta[o] - mean*sc;
}

// ---------------- K7: out[c][n] = x + relu(h*sc+sh)  (LDS transpose of h[n][o])
__global__ void k_final(const float* __restrict__ x, const short* __restrict__ h,
                        const float* __restrict__ bnsc, const float* __restrict__ bnsh,
                        float* __restrict__ out){
  int b = blockIdx.z, c0 = blockIdx.y*64, n0 = blockIdx.x*64;
  int tid = threadIdx.x;
  __shared__ float ht[64][65];
  {
    int n = tid>>2, ii = tid&3;
    #pragma unroll
    for(int p = 0; p < 2; ++p){
      int coff = 32*p + 8*ii;
      bf16x8 hv = *(const bf16x8*)(h + ((size_t)(b*N_ + n0 + n))*C_ + c0 + coff);
      #pragma unroll
      for(int jq = 0; jq < 8; ++jq) ht[n][coff + jq] = bf2f(hv[jq]);
    }
  }
  __syncthreads();
  int c = tid>>2, i2 = tid&3;
  float sc = bnsc[c0 + c], sh = bnsh[c0 + c];
  const float* xr = x + ((size_t)b*C_ + c0 + c)*N_ + n0 + 16*i2;
  float* orow = out + ((size_t)b*C_ + c0 + c)*N_ + n0 + 16*i2;
  #pragma unroll
  for(int k = 0; k < 16; k += 4){
    f32x4 xv = *(const f32x4*)(xr + k);
    f32x4 ov;
    #pragma unroll
    for(int jq = 0; jq < 4; ++jq){
      float bn = ht[16*i2 + k + jq][c]*sc + sh;
      ov[jq] = xv[jq] + fmaxf(bn, 0.f);
    }
    *(f32x4*)(orow + k) = ov;
  }
}

extern "C" void kernel_launch(void* const* d_in, const int* in_sizes, int n_in,
                              void* d_out, int out_size, void* d_ws, size_t ws_size,
                              hipStream_t stream){
  const float* x     = (const float*)d_in[0];
  const float* Wq    = (const float*)d_in[1];
  const float* Wk    = (const float*)d_in[2];
  const float* Wv    = (const float*)d_in[3];
  const float* Wl    = (const float*)d_in[4];
  const float* gamma = (const float*)d_in[5];
  const float* beta  = (const float*)d_in[6];
  float* out = (float*)d_out;

  char* p = (char*)d_ws;
  double* g    = (double*)p; p += (size_t)B_*C_*8;
  double* xsum = (double*)p; p += (size_t)B_*C_*8;
  short* Wb   = (short*)p;  p += (size_t)384*C_*2;
  short* Wlf  = (short*)p;  p += (size_t)C_*C_*2;
  short* qbuf = (short*)p;  p += (size_t)B_*N_*64*2;
  short* kf   = (short*)p;  p += (size_t)B_*N_*64*2;
  short* vf   = (short*)p;  p += (size_t)B_*C_*N_*2;
  short* xTb  = (short*)p;  p += (size_t)B_*N_*C_*2;
  short* att  = (short*)p;  p += (size_t)B_*N_*C_*2;
  float* bnsum= (float*)p;  p += C_*4;
  float* bnssq= (float*)p;  p += C_*4;
  float* bnsc = (float*)p;  p += C_*4;
  float* bnsh = (float*)p;  p += C_*4;
  short* h = vf;   // alias: vf fully consumed by k_attn before k_hgemm writes h

  (void)hipMemsetAsync(bnsum, 0, 2*C_*sizeof(float), stream);

  k_convw  <<<384, 256, 0, stream>>>(Wq, Wk, Wv, Wl, Wb, Wlf);
  k_xsum   <<<dim3(C_/4, B_), 256, 0, stream>>>(x, xsum);
  k_prep_g2<<<B_, 256, 0, stream>>>(xsum, Wq, Wk, g);
  k_qkv    <<<dim3(N_/64, B_), 256, 0, stream>>>(x, Wb, g, qbuf, kf, vf, xTb);
  k_attn   <<<512, 256, 0, stream>>>(qbuf, kf, vf, att);
  k_hgemm  <<<dim3(N_/64, B_), 256, 0, stream>>>(xTb, att, Wlf, h, bnsum, bnssq);
  k_bnfin  <<<1, 256, 0, stream>>>(bnsum, bnssq, gamma, beta, bnsc, bnsh);
  k_final  <<<dim3(N_/64, C_/64, B_), 256, 0, stream>>>(x, h, bnsc, bnsh, out);
}

// Round 10
// 159.996 us; speedup vs baseline: 2.8213x; 1.2534x over previous
//
#include <hip/hip_runtime.h>

#define B_ 16
#define C_ 256
#define N_ 2048
#define CK_ 64

using f32x4  = __attribute__((ext_vector_type(4))) float;
using bf16x8 = __attribute__((ext_vector_type(8))) short;
using short4_t = __attribute__((ext_vector_type(4))) short;

static __device__ __forceinline__ float bf2f(short s){
  unsigned u = ((unsigned)(unsigned short)s) << 16;
  float f; __builtin_memcpy(&f, &u, 4); return f;
}
static __device__ __forceinline__ short f2bf(float f){
  unsigned u; __builtin_memcpy(&u, &f, 4);
  unsigned r = (u + 0x7fffu + ((u >> 16) & 1u)) >> 16;   // RNE
  return (short)(unsigned short)r;
}

// XOR-swizzled byte offsets (128B pair-rows) for k_attn's V/p LDS tiles.
static __device__ __forceinline__ int vf_off(int cp, int ck){   // cp 0..255, ck 0..3 -> within 16KB
  int q = cp >> 1; int ch = (((cp & 1) << 2) | ck) ^ (q & 7);
  return q*128 + ch*16;
}
static __device__ __forceinline__ int p_off(int n, int ck){     // n 0..63, ck 0..3 -> within 8KB
  int q = n >> 1; int ch = (((n & 1) << 2) | ck) ^ (q & 7);
  return q*128 + ch*16;
}

// ---------------- K0: weights -> bf16. Wb rows: [0,64)=Wq, [64,128)=Wk, [128,384)=Wv.
// Wlf: Wl in exact MFMA A-fragment order.
__global__ void k_convw(const float* __restrict__ Wq, const float* __restrict__ Wk,
                        const float* __restrict__ Wv, const float* __restrict__ Wl,
                        short* __restrict__ Wb, short* __restrict__ Wlf){
  int i = blockIdx.x*256 + threadIdx.x;
  if(i < 384*C_){
    int o = i >> 8;
    float v;
    if(o < 64)       v = Wq[i];
    else if(o < 128) v = Wk[i - 64*C_];
    else             v = Wv[i - 128*C_];
    Wb[i] = f2bf(v);
  }
  if(i < C_*C_){
    int o = i >> 8, c = i & 255;
    int dest = (c>>5)*8192 + (o>>4)*512 + ((((c>>3)&3)*16) + (o&15))*8 + (c&7);
    Wlf[dest] = f2bf(Wl[i]);
  }
}

// ---------------- K1a: xsum[b,c] = sum_n x[b,c,n]  (f64, wave-per-row)
__global__ void k_xsum(const float* __restrict__ x, double* __restrict__ xsum){
  int b = blockIdx.y;
  int c = blockIdx.x*4 + (threadIdx.x>>6);
  int l = threadIdx.x & 63;
  const float* row = x + ((size_t)b*C_ + c)*N_;
  double s = 0.0;
  #pragma unroll
  for(int it = 0; it < 8; ++it){
    f32x4 v = *(const f32x4*)(row + it*256 + l*4);
    s += (double)v[0] + (double)v[1] + (double)v[2] + (double)v[3];
  }
  for(int off = 32; off; off >>= 1) s += __shfl_down(s, off);
  if(l == 0) xsum[b*C_ + c] = s;
}

// ---------------- K1b: g[b,:] = Wk^T (Wq xsum)   (f64 exact colsum prep, tiny)
__global__ void k_prep_g2(const double* __restrict__ xsum, const float* __restrict__ Wq,
                          const float* __restrict__ Wk, double* __restrict__ g){
  int b = blockIdx.x;
  __shared__ double xs[C_];
  __shared__ double t[CK_];
  int tid = threadIdx.x;
  xs[tid] = xsum[b*C_ + tid];
  __syncthreads();
  if(tid < CK_){
    double s = 0.0;
    const float* wr = Wq + (size_t)tid*C_;
    for(int c = 0; c < C_; ++c) s += (double)wr[c]*xs[c];
    t[tid] = s;
  }
  __syncthreads();
  double s = 0.0;
  for(int j = 0; j < CK_; ++j) s += (double)Wk[(size_t)j*C_ + tid]*t[j];
  g[b*C_ + tid] = s;
}

// ---------------- K3: QKV projection (unchanged from round 9)
__global__ __launch_bounds__(256,2) void k_qkv(const float* __restrict__ x,
        const short* __restrict__ Wb, const double* __restrict__ gg,
        short* __restrict__ qbuf, short* __restrict__ kf, short* __restrict__ vf,
        short* __restrict__ xTb){
  int b = blockIdx.y; int n0 = blockIdx.x*64;
  int tid = threadIdx.x, w = tid>>6, l = tid&63, lo = l&15, g = l>>4;
  __shared__ __attribute__((aligned(16))) short xT[64][40];   // [n][c-chunk], 80B rows
  __shared__ double gs[C_];
  __shared__ double csum[4][64];
  __shared__ float inv_lds[64];
  const float* xb = x + (size_t)b*C_*N_;
  gs[tid] = gg[b*C_ + tid];
  f32x4 acc[6][4];
  #pragma unroll
  for(int oi=0;oi<6;++oi) for(int nj=0;nj<4;++nj) acc[oi][nj]=(f32x4){0.f,0.f,0.f,0.f};
  double cs = 0.0;
  int n2 = tid>>2, ii2 = tid&3;
  short* xtb = xTb + ((size_t)b*N_ + n0)*C_;
  for(int cc = 0; cc < C_; cc += 32){
    __syncthreads();
    #pragma unroll
    for(int kk = 0; kk < 4; ++kk){             // stage x^T (pair-packed b32 writes)
      int pp = w + 4*kk;
      int ci = cc + 2*pp;
      float a  = xb[(size_t)ci*N_ + n0 + l];
      float c2 = xb[(size_t)(ci+1)*N_ + n0 + l];
      cs += (double)a*gs[ci] + (double)c2*gs[ci+1];
      unsigned pr = (unsigned)(unsigned short)f2bf(a) | (((unsigned)(unsigned short)f2bf(c2))<<16);
      *(unsigned*)(&xT[l][2*pp]) = pr;
    }
    __syncthreads();
    // write-back x^T bf16 to global (b128, 64B segments)
    *(bf16x8*)(xtb + (size_t)n2*C_ + cc + 8*ii2) = *(const bf16x8*)(&xT[n2][8*ii2]);
    bf16x8 bfr[4];
    #pragma unroll
    for(int nj = 0; nj < 4; ++nj) bfr[nj] = *(const bf16x8*)(&xT[nj*16 + lo][8*g]);
    #pragma unroll
    for(int oi = 0; oi < 6; ++oi){
      int o = w*96 + oi*16 + lo;
      bf16x8 af = *(const bf16x8*)(Wb + (size_t)o*C_ + cc + 8*g);
      #pragma unroll
      for(int nj = 0; nj < 4; ++nj)
        acc[oi][nj] = __builtin_amdgcn_mfma_f32_16x16x32_bf16(af, bfr[nj], acc[oi][nj], 0,0,0);
    }
  }
  __syncthreads();
  csum[w][l] = cs;
  __syncthreads();
  if(tid < 64){
    double t = csum[0][tid] + csum[1][tid] + csum[2][tid] + csum[3][tid];
    inv_lds[tid] = (float)(1.0/(1e-9 + t));
  }
  __syncthreads();

  short* qb  = qbuf + (size_t)b*N_*64;
  short* kfb = kf   + (size_t)b*N_*64;
  short* vfb = vf   + (size_t)b*C_*N_;
  #pragma unroll
  for(int oi = 0; oi < 6; ++oi){
    int obase = w*96 + oi*16;
    for(int nj = 0; nj < 4; ++nj){
      int n = n0 + nj*16 + lo;
      if(obase < 64){                          // Q rows
        short4_t pk;
        #pragma unroll
        for(int r = 0; r < 4; ++r) pk[r] = f2bf(acc[oi][nj][r]);
        *(short4_t*)(qb + (size_t)n*64 + obase + 4*g) = pk;
      } else if(obase < 128){                  // K fragments
        int C0 = obase - 64 + 4*g;
        int mt = (n0>>4) + nj;
        int h  = C0 >> 5;
        int lanep = ((C0>>3)&3)*16 + lo;
        short4_t pk;
        #pragma unroll
        for(int r = 0; r < 4; ++r) pk[r] = f2bf(acc[oi][nj][r]);
        *(short4_t*)(kfb + ((size_t)(mt*2 + h)*64 + lanep)*8 + (C0&4)) = pk;
      } else {                                 // V pre-swizzled
        float iv = inv_lds[nj*16 + lo];
        int ckk = (n>>3)&3, wi = n&7, mc = n>>5;
        #pragma unroll
        for(int r = 0; r < 4; ++r){
          int cp = obase - 128 + 4*g + r;
          vfb[(size_t)mc*8192 + (vf_off(cp, ckk)>>1) + wi] = f2bf(acc[oi][nj][r]*iv);
        }
      }
    }
  }
}

// ---------------- K4: attention (unchanged from round 8/9's passing version)
__global__ __launch_bounds__(256,2) void k_attn(const short* __restrict__ qbuf,
        const short* __restrict__ kf, const short* __restrict__ vf,
        short* __restrict__ att){
  int d = blockIdx.x;
  int xcd = d & 7, j = d >> 3;
  int b = xcd*2 + (j >> 5);
  int n0 = (j & 31)*64;
  int tid = threadIdx.x;
  int w = tid>>6, l = tid&63, lo = l&15, g = l>>4;

  __shared__ short vlds[2][8192];
  __shared__ short plds[2][4096];
  __shared__ float rs_lds[64];

  const short* qb  = qbuf + (size_t)b*N_*64;
  const short* kfb = kf   + (size_t)b*N_*64;
  const short* vfb = vf   + (size_t)b*C_*N_;

  bf16x8 qa0, qa1;
  {
    const short* qrow = qb + (size_t)(n0 + w*16 + lo)*64;
    qa0 = *(const bf16x8*)(qrow + 8*g);
    qa1 = *(const bf16x8*)(qrow + 32 + 8*g);
  }
  int paoff[4], bvoff[4];
  #pragma unroll
  for(int rt = 0; rt < 4; ++rt) paoff[rt] = p_off(rt*16 + lo, g);
  #pragma unroll
  for(int jj = 0; jj < 4; ++jj) bvoff[jj] = vf_off(w*64 + jj*16 + lo, g);
  int pw0 = p_off(w*16 + lo, (g>>1))     + (g&1)*8;
  int pw1 = p_off(w*16 + lo, 2 + (g>>1)) + (g&1)*8;

  const short* kl   = kfb + l*8;
  const short* vsrc = vfb + w*2048 + l*8;

  f32x4 oacc[4][4];
  #pragma unroll
  for(int rt=0;rt<4;++rt) for(int jj=0;jj<4;++jj) oacc[rt][jj]=(f32x4){0.f,0.f,0.f,0.f};
  float srow = 0.f;

  bf16x8 kb00, kb01, kb10, kb11;

#define LOADK(MC) { const short* kp = kl + (size_t)(MC)*2048; \
    kb00 = *(const bf16x8*)(kp);        kb01 = *(const bf16x8*)(kp + 512); \
    kb10 = *(const bf16x8*)(kp + 1024); kb11 = *(const bf16x8*)(kp + 1536); }
#define GLLDS(SRC, DST) __builtin_amdgcn_global_load_lds( \
    (const __attribute__((address_space(1))) void*)(SRC), \
    (__attribute__((address_space(3))) void*)(DST), 16, 0, 0)
#define VDMA(MC, NB) { const short* vs = vsrc + (size_t)(MC)*8192; \
    GLLDS(vs,        (char*)&vlds[NB][0] + w*4096);        \
    GLLDS(vs +  512, (char*)&vlds[NB][0] + w*4096 + 1024); \
    GLLDS(vs + 1024, (char*)&vlds[NB][0] + w*4096 + 2048); \
    GLLDS(vs + 1536, (char*)&vlds[NB][0] + w*4096 + 3072); }

  LOADK(0);
  VDMA(0, 0);

#define BODY(BUF, MC) { \
    f32x4 a0 = (f32x4){0.f,0.f,0.f,0.f}, a1 = (f32x4){0.f,0.f,0.f,0.f}; \
    a0 = __builtin_amdgcn_mfma_f32_16x16x32_bf16(kb00, qa0, a0, 0,0,0); \
    a0 = __builtin_amdgcn_mfma_f32_16x16x32_bf16(kb01, qa1, a0, 0,0,0); \
    a1 = __builtin_amdgcn_mfma_f32_16x16x32_bf16(kb10, qa0, a1, 0,0,0); \
    a1 = __builtin_amdgcn_mfma_f32_16x16x32_bf16(kb11, qa1, a1, 0,0,0); \
    short4_t pk0, pk1; \
    _Pragma("unroll") \
    for(int r = 0; r < 4; ++r){ \
      float e0 = __builtin_exp2f(fmaf(a0[r], 1.44269504f, -17.3123405f)); \
      float e1 = __builtin_exp2f(fmaf(a1[r], 1.44269504f, -17.3123405f)); \
      srow += e0 + e1; pk0[r] = f2bf(e0); pk1[r] = f2bf(e1); } \
    *(short4_t*)((char*)&plds[BUF][0] + pw0) = pk0; \
    *(short4_t*)((char*)&plds[BUF][0] + pw1) = pk1; \
    { int mn = ((MC) + 1) & 63; \
      LOADK(mn); \
      VDMA(mn, (BUF)^1); } \
    __builtin_amdgcn_sched_barrier(0); \
    asm volatile("s_waitcnt vmcnt(8) lgkmcnt(0)" ::: "memory"); \
    __builtin_amdgcn_s_barrier(); \
    __builtin_amdgcn_sched_barrier(0); \
    bf16x8 pa[4], bv[4]; \
    _Pragma("unroll") \
    for(int rt = 0; rt < 4; ++rt) pa[rt] = *(const bf16x8*)((char*)&plds[BUF][0] + paoff[rt]); \
    _Pragma("unroll") \
    for(int jj = 0; jj < 4; ++jj) bv[jj] = *(const bf16x8*)((char*)&vlds[BUF][0] + bvoff[jj]); \
    _Pragma("unroll") \
    for(int rt = 0; rt < 4; ++rt) \
      _Pragma("unroll") \
      for(int jj = 0; jj < 4; ++jj) \
        oacc[rt][jj] = __builtin_amdgcn_mfma_f32_16x16x32_bf16(pa[rt], bv[jj], oacc[rt][jj], 0,0,0); }

  #pragma unroll 1
  for(int it = 0; it < 32; ++it){
    BODY(0, 2*it);
    BODY(1, 2*it + 1);
  }
#undef BODY
#undef VDMA
#undef GLLDS
#undef LOADK

  float S = srow;
  S += __shfl_xor(S, 16);
  S += __shfl_xor(S, 32);
  if(l < 16) rs_lds[w*16 + l] = 1.f/(S + 1e-30f);
  __syncthreads();
  float rinvs[4][4];
  #pragma unroll
  for(int rt = 0; rt < 4; ++rt)
    #pragma unroll
    for(int r = 0; r < 4; ++r) rinvs[rt][r] = rs_lds[rt*16 + 4*g + r];

  short* attb = att + (size_t)b*N_*C_;
  #pragma unroll
  for(int rt = 0; rt < 4; ++rt)
    #pragma unroll
    for(int jj = 0; jj < 4; ++jj)
      #pragma unroll
      for(int r = 0; r < 4; ++r){
        int n = n0 + rt*16 + 4*g + r;
        int c = w*64 + jj*16 + lo;
        attb[(size_t)n*C_ + c] = f2bf(oacc[rt][jj][r]*rinvs[rt][r]);
      }
}

// ---------------- K5: h[n][o] = sum_c Wl[o,c]*(xT[n,c]-att[n,c]); BN partials
// to global (NO atomics: each wave owns a disjoint 64-channel range).
__global__ __launch_bounds__(256,2) void k_hgemm(const short* __restrict__ xTb,
        const short* __restrict__ att, const short* __restrict__ Wlf,
        short* __restrict__ h, float* __restrict__ part){
  int b = blockIdx.y; int n0 = blockIdx.x*64;
  int bid = b*32 + blockIdx.x;
  int tid = threadIdx.x, w = tid>>6, l = tid&63, lo = l&15, g = l>>4;
  __shared__ __attribute__((aligned(16))) short rT[64*C_];   // swizzled [n][ch^(n&7)]
  const short* xtb = xTb + ((size_t)b*N_ + n0)*C_;
  const short* atb = att + ((size_t)b*N_ + n0)*C_;
  int half = l >> 5, ch = l & 31;
  #pragma unroll
  for(int k = 0; k < 8; ++k){                  // 1KB fully-coalesced loads, 2 rows/instr
    int n = k*8 + w*2 + half;
    size_t off = (size_t)n*C_ + ch*8;
    bf16x8 xv = *(const bf16x8*)(xtb + off);
    bf16x8 av = *(const bf16x8*)(atb + off);
    bf16x8 rv;
    #pragma unroll
    for(int jq = 0; jq < 8; ++jq) rv[jq] = f2bf(bf2f(xv[jq]) - bf2f(av[jq]));
    *(bf16x8*)(&rT[n*C_ + ((ch ^ (n&7))*8)]) = rv;
  }
  __syncthreads();

  f32x4 acc[4][4];
  #pragma unroll
  for(int ot=0;ot<4;++ot) for(int nj=0;nj<4;++nj) acc[ot][nj]=(f32x4){0.f,0.f,0.f,0.f};
  #pragma unroll
  for(int cb = 0; cb < 8; ++cb){               // cc = cb*32, no barriers needed
    bf16x8 bfr[4];
    #pragma unroll
    for(int nj = 0; nj < 4; ++nj)
      bfr[nj] = *(const bf16x8*)(&rT[(nj*16 + lo)*C_ + (((cb*4 + g) ^ (lo&7))*8)]);
    #pragma unroll
    for(int ot = 0; ot < 4; ++ot){
      bf16x8 af = *(const bf16x8*)(Wlf + ((size_t)(cb*16 + w*4 + ot))*512 + l*8);
      #pragma unroll
      for(int nj = 0; nj < 4; ++nj)
        acc[ot][nj] = __builtin_amdgcn_mfma_f32_16x16x32_bf16(af, bfr[nj], acc[ot][nj], 0,0,0);
    }
  }
  short* hb = h + (size_t)b*N_*C_;
  #pragma unroll
  for(int ot = 0; ot < 4; ++ot)
    for(int nj = 0; nj < 4; ++nj){
      int n = n0 + nj*16 + lo;
      short4_t pk;
      #pragma unroll
      for(int r = 0; r < 4; ++r) pk[r] = f2bf(acc[ot][nj][r]);
      *(short4_t*)(&hb[(size_t)n*C_ + w*64 + ot*16 + 4*g]) = pk;
    }
  float* pr_ = part + (size_t)bid*512;
  #pragma unroll
  for(int ot = 0; ot < 4; ++ot){
    float s4[4] = {0,0,0,0}, q4[4] = {0,0,0,0};
    for(int nj = 0; nj < 4; ++nj)
      #pragma unroll
      for(int r = 0; r < 4; ++r){ float v = acc[ot][nj][r]; s4[r] += v; q4[r] += v*v; }
    #pragma unroll
    for(int r = 0; r < 4; ++r){
      float ss = s4[r], qq = q4[r];
      for(int msk = 1; msk < 16; msk <<= 1){ ss += __shfl_xor(ss, msk); qq += __shfl_xor(qq, msk); }
      if(lo == 0){
        int o = w*64 + ot*16 + 4*g + r;
        pr_[o] = ss;
        pr_[256 + o] = qq;
      }
    }
  }
}

// ---------------- K6: BN reduce (512 partial rows) + finalize scale/shift
__global__ void k_bnfin(const float* __restrict__ part,
                        const float* __restrict__ gamma, const float* __restrict__ beta,
                        float* __restrict__ bnsc, float* __restrict__ bnsh){
  __shared__ float ls[4][512];
  int t = threadIdx.x; int o = t & 255, seg = t >> 8;   // 1024 threads
  float s = 0.f, q = 0.f;
  for(int r = seg*128; r < seg*128 + 128; ++r){
    s += part[(size_t)r*512 + o];
    q += part[(size_t)r*512 + 256 + o];
  }
  ls[seg][o] = s; ls[seg][256 + o] = q;
  __syncthreads();
  if(t < 256){
    float S = ls[0][t] + ls[1][t] + ls[2][t] + ls[3][t];
    float Q = ls[0][256+t] + ls[1][256+t] + ls[2][256+t] + ls[3][256+t];
    float cnt = (float)(B_*N_);
    float mean = S/cnt;
    float var  = Q/cnt - mean*mean;
    float is   = rsqrtf(var + 1e-5f);
    float sc   = gamma[t]*is;
    bnsc[t] = sc;
    bnsh[t] = beta[t] - mean*sc;
  }
}

// ---------------- K7: out[c][n] = x + relu(h*sc+sh)  (LDS transpose of h[n][o])
__global__ void k_final(const float* __restrict__ x, const short* __restrict__ h,
                        const float* __restrict__ bnsc, const float* __restrict__ bnsh,
                        float* __restrict__ out){
  int b = blockIdx.z, c0 = blockIdx.y*64, n0 = blockIdx.x*64;
  int tid = threadIdx.x;
  __shared__ float ht[64][65];
  {
    int n = tid>>2, ii = tid&3;
    #pragma unroll
    for(int p = 0; p < 2; ++p){
      int coff = 32*p + 8*ii;
      bf16x8 hv = *(const bf16x8*)(h + ((size_t)(b*N_ + n0 + n))*C_ + c0 + coff);
      #pragma unroll
      for(int jq = 0; jq < 8; ++jq) ht[n][coff + jq] = bf2f(hv[jq]);
    }
  }
  __syncthreads();
  int c = tid>>2, i2 = tid&3;
  float sc = bnsc[c0 + c], sh = bnsh[c0 + c];
  const float* xr = x + ((size_t)b*C_ + c0 + c)*N_ + n0 + 16*i2;
  float* orow = out + ((size_t)b*C_ + c0 + c)*N_ + n0 + 16*i2;
  #pragma unroll
  for(int k = 0; k < 16; k += 4){
    f32x4 xv = *(const f32x4*)(xr + k);
    f32x4 ov;
    #pragma unroll
    for(int jq = 0; jq < 4; ++jq){
      float bn = ht[16*i2 + k + jq][c]*sc + sh;
      ov[jq] = xv[jq] + fmaxf(bn, 0.f);
    }
    *(f32x4*)(orow + k) = ov;
  }
}

extern "C" void kernel_launch(void* const* d_in, const int* in_sizes, int n_in,
                              void* d_out, int out_size, void* d_ws, size_t ws_size,
                              hipStream_t stream){
  const float* x     = (const float*)d_in[0];
  const float* Wq    = (const float*)d_in[1];
  const float* Wk    = (const float*)d_in[2];
  const float* Wv    = (const float*)d_in[3];
  const float* Wl    = (const float*)d_in[4];
  const float* gamma = (const float*)d_in[5];
  const float* beta  = (const float*)d_in[6];
  float* out = (float*)d_out;

  char* p = (char*)d_ws;
  double* g    = (double*)p; p += (size_t)B_*C_*8;
  double* xsum = (double*)p; p += (size_t)B_*C_*8;
  short* Wb   = (short*)p;  p += (size_t)384*C_*2;
  short* Wlf  = (short*)p;  p += (size_t)C_*C_*2;
  short* qbuf = (short*)p;  p += (size_t)B_*N_*64*2;
  short* kf   = (short*)p;  p += (size_t)B_*N_*64*2;
  short* vf   = (short*)p;  p += (size_t)B_*C_*N_*2;
  short* xTb  = (short*)p;  p += (size_t)B_*N_*C_*2;
  short* att  = (short*)p;  p += (size_t)B_*N_*C_*2;
  float* part = (float*)p;  p += (size_t)512*512*4;
  float* bnsc = (float*)p;  p += C_*4;
  float* bnsh = (float*)p;  p += C_*4;
  short* h = vf;   // alias: vf fully consumed by k_attn before k_hgemm writes h

  k_convw  <<<384, 256, 0, stream>>>(Wq, Wk, Wv, Wl, Wb, Wlf);
  k_xsum   <<<dim3(C_/4, B_), 256, 0, stream>>>(x, xsum);
  k_prep_g2<<<B_, 256, 0, stream>>>(xsum, Wq, Wk, g);
  k_qkv    <<<dim3(N_/64, B_), 256, 0, stream>>>(x, Wb, g, qbuf, kf, vf, xTb);
  k_attn   <<<512, 256, 0, stream>>>(qbuf, kf, vf, att);
  k_hgemm  <<<dim3(N_/64, B_), 256, 0, stream>>>(xTb, att, Wlf, h, part);
  k_bnfin  <<<1, 1024, 0, stream>>>(part, gamma, beta, bnsc, bnsh);
  k_final  <<<dim3(N_/64, C_/64, B_), 256, 0, stream>>>(x, h, bnsc, bnsh, out);
}

// Round 11
// 156.638 us; speedup vs baseline: 2.8818x; 1.0214x over previous
//
#include <hip/hip_runtime.h>

#define B_ 16
#define C_ 256
#define N_ 2048
#define CK_ 64

using f32x4  = __attribute__((ext_vector_type(4))) float;
using bf16x8 = __attribute__((ext_vector_type(8))) short;
using short4_t = __attribute__((ext_vector_type(4))) short;
using u32x2  = __attribute__((ext_vector_type(2))) unsigned;

static __device__ __forceinline__ float bf2f(short s){
  unsigned u = ((unsigned)(unsigned short)s) << 16;
  float f; __builtin_memcpy(&f, &u, 4); return f;
}
static __device__ __forceinline__ short f2bf(float f){
  unsigned u; __builtin_memcpy(&u, &f, 4);
  unsigned r = (u + 0x7fffu + ((u >> 16) & 1u)) >> 16;   // RNE
  return (short)(unsigned short)r;
}

// XOR-swizzled byte offsets (128B pair-rows) for k_attn's V/p LDS tiles.
static __device__ __forceinline__ int vf_off(int cp, int ck){   // cp 0..255, ck 0..3 -> within 16KB
  int q = cp >> 1; int ch = (((cp & 1) << 2) | ck) ^ (q & 7);
  return q*128 + ch*16;
}
static __device__ __forceinline__ int p_off(int n, int ck){     // n 0..63, ck 0..3 -> within 8KB
  int q = n >> 1; int ch = (((n & 1) << 2) | ck) ^ (q & 7);
  return q*128 + ch*16;
}

// ---------------- K0: weights -> bf16. Wb rows: [0,64)=Wq, [64,128)=Wk, [128,384)=Wv.
// Wlf: Wl in exact MFMA A-fragment order.
__global__ void k_convw(const float* __restrict__ Wq, const float* __restrict__ Wk,
                        const float* __restrict__ Wv, const float* __restrict__ Wl,
                        short* __restrict__ Wb, short* __restrict__ Wlf){
  int i = blockIdx.x*256 + threadIdx.x;
  if(i < 384*C_){
    int o = i >> 8;
    float v;
    if(o < 64)       v = Wq[i];
    else if(o < 128) v = Wk[i - 64*C_];
    else             v = Wv[i - 128*C_];
    Wb[i] = f2bf(v);
  }
  if(i < C_*C_){
    int o = i >> 8, c = i & 255;
    int dest = (c>>5)*8192 + (o>>4)*512 + ((((c>>3)&3)*16) + (o&15))*8 + (c&7);
    Wlf[dest] = f2bf(Wl[i]);
  }
}

// ---------------- K1a: xsum[b,c] = sum_n x[b,c,n]  (f64, wave-per-row)
__global__ void k_xsum(const float* __restrict__ x, double* __restrict__ xsum){
  int b = blockIdx.y;
  int c = blockIdx.x*4 + (threadIdx.x>>6);
  int l = threadIdx.x & 63;
  const float* row = x + ((size_t)b*C_ + c)*N_;
  double s = 0.0;
  #pragma unroll
  for(int it = 0; it < 8; ++it){
    f32x4 v = *(const f32x4*)(row + it*256 + l*4);
    s += (double)v[0] + (double)v[1] + (double)v[2] + (double)v[3];
  }
  for(int off = 32; off; off >>= 1) s += __shfl_down(s, off);
  if(l == 0) xsum[b*C_ + c] = s;
}

// ---------------- K1b: g[b,:] = Wk^T (Wq xsum)   (f64 exact colsum prep, tiny)
__global__ void k_prep_g2(const double* __restrict__ xsum, const float* __restrict__ Wq,
                          const float* __restrict__ Wk, double* __restrict__ g){
  int b = blockIdx.x;
  __shared__ double xs[C_];
  __shared__ double t[CK_];
  int tid = threadIdx.x;
  xs[tid] = xsum[b*C_ + tid];
  __syncthreads();
  if(tid < CK_){
    double s = 0.0;
    const float* wr = Wq + (size_t)tid*C_;
    for(int c = 0; c < C_; ++c) s += (double)wr[c]*xs[c];
    t[tid] = s;
  }
  __syncthreads();
  double s = 0.0;
  for(int j = 0; j < CK_; ++j) s += (double)Wk[(size_t)j*C_ + tid]*t[j];
  g[b*C_ + tid] = s;
}

// ---------------- K3: QKV projection, stage-once/compute-once (ONE barrier main path).
#define XROW 328   // shorts; 656B row: 16B-aligned, bank-stride 4 -> 2-way-free b128 reads
__global__ __launch_bounds__(256,2) void k_qkv(const float* __restrict__ x,
        const short* __restrict__ Wb, const double* __restrict__ gg,
        short* __restrict__ qbuf, short* __restrict__ kf, short* __restrict__ vf,
        short* __restrict__ xTb){
  int b = blockIdx.y; int n0 = blockIdx.x*64;
  int tid = threadIdx.x, w = tid>>6, l = tid&63, lo = l&15, g = l>>4;
  __shared__ __attribute__((aligned(16))) short xT[64*XROW];   // 41 KB
  __shared__ double gs[C_];
  __shared__ double csum[4][64];
  __shared__ float inv_lds[64];
  const float* xb = x + (size_t)b*C_*N_;
  gs[tid] = gg[b*C_ + tid];
  __syncthreads();
  double cs = 0.0;
  for(int cc = 0; cc < 8; ++cc){               // 64 coalesced scalar loads, no barriers
    #pragma unroll
    for(int kk = 0; kk < 4; ++kk){
      int pp = w + 4*kk;
      int ci = cc*32 + 2*pp;
      float a  = xb[(size_t)ci*N_ + n0 + l];
      float c2 = xb[(size_t)(ci+1)*N_ + n0 + l];
      cs += (double)a*gs[ci] + (double)c2*gs[ci+1];
      unsigned pr = (unsigned)(unsigned short)f2bf(a) | (((unsigned)(unsigned short)f2bf(c2))<<16);
      *(unsigned*)(&xT[l*XROW + cc*40 + 2*pp]) = pr;
    }
  }
  __syncthreads();                             // the ONE staging barrier

  f32x4 acc[6][4];
  #pragma unroll
  for(int oi=0;oi<6;++oi) for(int nj=0;nj<4;++nj) acc[oi][nj]=(f32x4){0.f,0.f,0.f,0.f};
  int n2 = tid>>2, ii2 = tid&3;
  short* xtb = xTb + ((size_t)b*N_ + n0)*C_;
  #pragma unroll
  for(int cc = 0; cc < 8; ++cc){
    // write-back x^T bf16 to global (b128)
    *(bf16x8*)(xtb + (size_t)n2*C_ + cc*32 + 8*ii2) =
        *(const bf16x8*)(&xT[n2*XROW + cc*40 + 8*ii2]);
    bf16x8 bfr[4];
    #pragma unroll
    for(int nj = 0; nj < 4; ++nj)
      bfr[nj] = *(const bf16x8*)(&xT[(nj*16 + lo)*XROW + cc*40 + 8*g]);
    #pragma unroll
    for(int oi = 0; oi < 6; ++oi){
      int o = w*96 + oi*16 + lo;
      bf16x8 af = *(const bf16x8*)(Wb + (size_t)o*C_ + cc*32 + 8*g);
      #pragma unroll
      for(int nj = 0; nj < 4; ++nj)
        acc[oi][nj] = __builtin_amdgcn_mfma_f32_16x16x32_bf16(af, bfr[nj], acc[oi][nj], 0,0,0);
    }
  }
  csum[w][l] = cs;
  __syncthreads();
  if(tid < 64){
    double t = csum[0][tid] + csum[1][tid] + csum[2][tid] + csum[3][tid];
    inv_lds[tid] = (float)(1.0/(1e-9 + t));
  }
  __syncthreads();

  short* qb  = qbuf + (size_t)b*N_*64;
  short* kfb = kf   + (size_t)b*N_*64;
  short* vfb = vf   + (size_t)b*C_*N_;
  #pragma unroll
  for(int oi = 0; oi < 6; ++oi){
    int obase = w*96 + oi*16;
    for(int nj = 0; nj < 4; ++nj){
      int n = n0 + nj*16 + lo;
      if(obase < 64){                          // Q rows
        short4_t pk;
        #pragma unroll
        for(int r = 0; r < 4; ++r) pk[r] = f2bf(acc[oi][nj][r]);
        *(short4_t*)(qb + (size_t)n*64 + obase + 4*g) = pk;
      } else if(obase < 128){                  // K fragments
        int C0 = obase - 64 + 4*g;
        int mt = (n0>>4) + nj;
        int h  = C0 >> 5;
        int lanep = ((C0>>3)&3)*16 + lo;
        short4_t pk;
        #pragma unroll
        for(int r = 0; r < 4; ++r) pk[r] = f2bf(acc[oi][nj][r]);
        *(short4_t*)(kfb + ((size_t)(mt*2 + h)*64 + lanep)*8 + (C0&4)) = pk;
      } else {                                 // V pre-swizzled
        float iv = inv_lds[nj*16 + lo];
        int ckk = (n>>3)&3, wi = n&7, mc = n>>5;
        #pragma unroll
        for(int r = 0; r < 4; ++r){
          int cp = obase - 128 + 4*g + r;
          vfb[(size_t)mc*8192 + (vf_off(cp, ckk)>>1) + wi] = f2bf(acc[oi][nj][r]*iv);
        }
      }
    }
  }
}
#undef XROW

// ---------------- K4: attention. 2-deep K prefetch (static reg sets), cvt_pk p-pack,
// double-buffered swizzled LDS, global_load_lds V staging, one barrier/iter vmcnt(8).
__global__ __launch_bounds__(256,2) void k_attn(const short* __restrict__ qbuf,
        const short* __restrict__ kf, const short* __restrict__ vf,
        short* __restrict__ att){
  int d = blockIdx.x;
  int xcd = d & 7, j = d >> 3;
  int b = xcd*2 + (j >> 5);
  int n0 = (j & 31)*64;
  int tid = threadIdx.x;
  int w = tid>>6, l = tid&63, lo = l&15, g = l>>4;

  __shared__ short vlds[2][8192];
  __shared__ short plds[2][4096];
  __shared__ float rs_lds[64];

  const short* qb  = qbuf + (size_t)b*N_*64;
  const short* kfb = kf   + (size_t)b*N_*64;
  const short* vfb = vf   + (size_t)b*C_*N_;

  bf16x8 qa0, qa1;
  {
    const short* qrow = qb + (size_t)(n0 + w*16 + lo)*64;
    qa0 = *(const bf16x8*)(qrow + 8*g);
    qa1 = *(const bf16x8*)(qrow + 32 + 8*g);
  }
  int paoff[4], bvoff[4];
  #pragma unroll
  for(int rt = 0; rt < 4; ++rt) paoff[rt] = p_off(rt*16 + lo, g);
  #pragma unroll
  for(int jj = 0; jj < 4; ++jj) bvoff[jj] = vf_off(w*64 + jj*16 + lo, g);
  int pw0 = p_off(w*16 + lo, (g>>1))     + (g&1)*8;
  int pw1 = p_off(w*16 + lo, 2 + (g>>1)) + (g&1)*8;

  const short* kl   = kfb + l*8;
  const short* vsrc = vfb + w*2048 + l*8;

  f32x4 oacc[4][4];
  #pragma unroll
  for(int rt=0;rt<4;++rt) for(int jj=0;jj<4;++jj) oacc[rt][jj]=(f32x4){0.f,0.f,0.f,0.f};
  float srow = 0.f;

  bf16x8 kbA0, kbA1, kbA2, kbA3;   // K set A (even bodies)
  bf16x8 kbB0, kbB1, kbB2, kbB3;   // K set B (odd bodies)

#define LOADK(S, MC) { const short* kp = kl + (size_t)((MC)&63)*2048; \
    kb##S##0 = *(const bf16x8*)(kp);        kb##S##1 = *(const bf16x8*)(kp + 512); \
    kb##S##2 = *(const bf16x8*)(kp + 1024); kb##S##3 = *(const bf16x8*)(kp + 1536); }
#define GLLDS(SRC, DST) __builtin_amdgcn_global_load_lds( \
    (const __attribute__((address_space(1))) void*)(SRC), \
    (__attribute__((address_space(3))) void*)(DST), 16, 0, 0)
#define VDMA(MC, NB) { const short* vs = vsrc + (size_t)(MC)*8192; \
    GLLDS(vs,        (char*)&vlds[NB][0] + w*4096);        \
    GLLDS(vs +  512, (char*)&vlds[NB][0] + w*4096 + 1024); \
    GLLDS(vs + 1024, (char*)&vlds[NB][0] + w*4096 + 2048); \
    GLLDS(vs + 1536, (char*)&vlds[NB][0] + w*4096 + 3072); }

  // prologue: K(0)->A, K(1)->B, V(0)->buf0
  LOADK(A, 0);
  LOADK(B, 1);
  VDMA(0, 0);

#define BODY(BUF, S, MC) { \
    f32x4 a0 = (f32x4){0.f,0.f,0.f,0.f}, a1 = (f32x4){0.f,0.f,0.f,0.f}; \
    a0 = __builtin_amdgcn_mfma_f32_16x16x32_bf16(kb##S##0, qa0, a0, 0,0,0); \
    a0 = __builtin_amdgcn_mfma_f32_16x16x32_bf16(kb##S##1, qa1, a0, 0,0,0); \
    a1 = __builtin_amdgcn_mfma_f32_16x16x32_bf16(kb##S##2, qa0, a1, 0,0,0); \
    a1 = __builtin_amdgcn_mfma_f32_16x16x32_bf16(kb##S##3, qa1, a1, 0,0,0); \
    float e0[4], e1[4]; \
    _Pragma("unroll") \
    for(int r = 0; r < 4; ++r){ \
      e0[r] = __builtin_exp2f(fmaf(a0[r], 1.44269504f, -17.3123405f)); \
      e1[r] = __builtin_exp2f(fmaf(a1[r], 1.44269504f, -17.3123405f)); } \
    srow += (e0[0]+e0[1]+e0[2]+e0[3]) + (e1[0]+e1[1]+e1[2]+e1[3]); \
    unsigned q00,q01,q10,q11; \
    asm("v_cvt_pk_bf16_f32 %0, %1, %2" : "=v"(q00) : "v"(e0[0]), "v"(e0[1])); \
    asm("v_cvt_pk_bf16_f32 %0, %1, %2" : "=v"(q01) : "v"(e0[2]), "v"(e0[3])); \
    asm("v_cvt_pk_bf16_f32 %0, %1, %2" : "=v"(q10) : "v"(e1[0]), "v"(e1[1])); \
    asm("v_cvt_pk_bf16_f32 %0, %1, %2" : "=v"(q11) : "v"(e1[2]), "v"(e1[3])); \
    { u32x2 w0v = {q00,q01}, w1v = {q10,q11}; \
      *(u32x2*)((char*)&plds[BUF][0] + pw0) = w0v; \
      *(u32x2*)((char*)&plds[BUF][0] + pw1) = w1v; } \
    LOADK(S, (MC)+2); \
    VDMA(((MC)+1)&63, (BUF)^1); \
    __builtin_amdgcn_sched_barrier(0); \
    asm volatile("s_waitcnt vmcnt(8) lgkmcnt(0)" ::: "memory"); \
    __builtin_amdgcn_s_barrier(); \
    __builtin_amdgcn_sched_barrier(0); \
    bf16x8 pa[4], bv[4]; \
    _Pragma("unroll") \
    for(int rt = 0; rt < 4; ++rt) pa[rt] = *(const bf16x8*)((char*)&plds[BUF][0] + paoff[rt]); \
    _Pragma("unroll") \
    for(int jj = 0; jj < 4; ++jj) bv[jj] = *(const bf16x8*)((char*)&vlds[BUF][0] + bvoff[jj]); \
    _Pragma("unroll") \
    for(int rt = 0; rt < 4; ++rt) \
      _Pragma("unroll") \
      for(int jj = 0; jj < 4; ++jj) \
        oacc[rt][jj] = __builtin_amdgcn_mfma_f32_16x16x32_bf16(pa[rt], bv[jj], oacc[rt][jj], 0,0,0); }

  #pragma unroll 1
  for(int it = 0; it < 32; ++it){
    BODY(0, A, 2*it);
    BODY(1, B, 2*it + 1);
  }
#undef BODY
#undef VDMA
#undef GLLDS
#undef LOADK

  float S = srow;
  S += __shfl_xor(S, 16);
  S += __shfl_xor(S, 32);
  if(l < 16) rs_lds[w*16 + l] = 1.f/(S + 1e-30f);
  __syncthreads();
  float rinvs[4][4];
  #pragma unroll
  for(int rt = 0; rt < 4; ++rt)
    #pragma unroll
    for(int r = 0; r < 4; ++r) rinvs[rt][r] = rs_lds[rt*16 + 4*g + r];

  short* attb = att + (size_t)b*N_*C_;
  #pragma unroll
  for(int rt = 0; rt < 4; ++rt)
    #pragma unroll
    for(int jj = 0; jj < 4; ++jj)
      #pragma unroll
      for(int r = 0; r < 4; ++r){
        int n = n0 + rt*16 + 4*g + r;
        int c = w*64 + jj*16 + lo;
        attb[(size_t)n*C_ + c] = f2bf(oacc[rt][jj][r]*rinvs[rt][r]);
      }
}

// ---------------- K5: h[n][o] = sum_c Wl[o,c]*(xT[n,c]-att[n,c]); BN partials
// to global (NO atomics: each wave owns a disjoint 64-channel range).
__global__ __launch_bounds__(256,2) void k_hgemm(const short* __restrict__ xTb,
        const short* __restrict__ att, const short* __restrict__ Wlf,
        short* __restrict__ h, float* __restrict__ part){
  int b = blockIdx.y; int n0 = blockIdx.x*64;
  int bid = b*32 + blockIdx.x;
  int tid = threadIdx.x, w = tid>>6, l = tid&63, lo = l&15, g = l>>4;
  __shared__ __attribute__((aligned(16))) short rT[64*C_];   // swizzled [n][ch^(n&7)]
  const short* xtb = xTb + ((size_t)b*N_ + n0)*C_;
  const short* atb = att + ((size_t)b*N_ + n0)*C_;
  int half = l >> 5, ch = l & 31;
  #pragma unroll
  for(int k = 0; k < 8; ++k){
    int n = k*8 + w*2 + half;
    size_t off = (size_t)n*C_ + ch*8;
    bf16x8 xv = *(const bf16x8*)(xtb + off);
    bf16x8 av = *(const bf16x8*)(atb + off);
    bf16x8 rv;
    #pragma unroll
    for(int jq = 0; jq < 8; ++jq) rv[jq] = f2bf(bf2f(xv[jq]) - bf2f(av[jq]));
    *(bf16x8*)(&rT[n*C_ + ((ch ^ (n&7))*8)]) = rv;
  }
  __syncthreads();

  f32x4 acc[4][4];
  #pragma unroll
  for(int ot=0;ot<4;++ot) for(int nj=0;nj<4;++nj) acc[ot][nj]=(f32x4){0.f,0.f,0.f,0.f};
  #pragma unroll
  for(int cb = 0; cb < 8; ++cb){
    bf16x8 bfr[4];
    #pragma unroll
    for(int nj = 0; nj < 4; ++nj)
      bfr[nj] = *(const bf16x8*)(&rT[(nj*16 + lo)*C_ + (((cb*4 + g) ^ (lo&7))*8)]);
    #pragma unroll
    for(int ot = 0; ot < 4; ++ot){
      bf16x8 af = *(const bf16x8*)(Wlf + ((size_t)(cb*16 + w*4 + ot))*512 + l*8);
      #pragma unroll
      for(int nj = 0; nj < 4; ++nj)
        acc[ot][nj] = __builtin_amdgcn_mfma_f32_16x16x32_bf16(af, bfr[nj], acc[ot][nj], 0,0,0);
    }
  }
  short* hb = h + (size_t)b*N_*C_;
  #pragma unroll
  for(int ot = 0; ot < 4; ++ot)
    for(int nj = 0; nj < 4; ++nj){
      int n = n0 + nj*16 + lo;
      short4_t pk;
      #pragma unroll
      for(int r = 0; r < 4; ++r) pk[r] = f2bf(acc[ot][nj][r]);
      *(short4_t*)(&hb[(size_t)n*C_ + w*64 + ot*16 + 4*g]) = pk;
    }
  float* pr_ = part + (size_t)bid*512;
  #pragma unroll
  for(int ot = 0; ot < 4; ++ot){
    float s4[4] = {0,0,0,0}, q4[4] = {0,0,0,0};
    for(int nj = 0; nj < 4; ++nj)
      #pragma unroll
      for(int r = 0; r < 4; ++r){ float v = acc[ot][nj][r]; s4[r] += v; q4[r] += v*v; }
    #pragma unroll
    for(int r = 0; r < 4; ++r){
      float ss = s4[r], qq = q4[r];
      for(int msk = 1; msk < 16; msk <<= 1){ ss += __shfl_xor(ss, msk); qq += __shfl_xor(qq, msk); }
      if(lo == 0){
        int o = w*64 + ot*16 + 4*g + r;
        pr_[o] = ss;
        pr_[256 + o] = qq;
      }
    }
  }
}

// ---------------- K6: BN reduce (512 partial rows) + finalize scale/shift
__global__ void k_bnfin(const float* __restrict__ part,
                        const float* __restrict__ gamma, const float* __restrict__ beta,
                        float* __restrict__ bnsc, float* __restrict__ bnsh){
  __shared__ float ls[4][512];
  int t = threadIdx.x; int o = t & 255, seg = t >> 8;   // 1024 threads
  float s = 0.f, q = 0.f;
  for(int r = seg*128; r < seg*128 + 128; ++r){
    s += part[(size_t)r*512 + o];
    q += part[(size_t)r*512 + 256 + o];
  }
  ls[seg][o] = s; ls[seg][256 + o] = q;
  __syncthreads();
  if(t < 256){
    float S = ls[0][t] + ls[1][t] + ls[2][t] + ls[3][t];
    float Q = ls[0][256+t] + ls[1][256+t] + ls[2][256+t] + ls[3][256+t];
    float cnt = (float)(B_*N_);
    float mean = S/cnt;
    float var  = Q/cnt - mean*mean;
    float is   = rsqrtf(var + 1e-5f);
    float sc   = gamma[t]*is;
    bnsc[t] = sc;
    bnsh[t] = beta[t] - mean*sc;
  }
}

// ---------------- K7: out[c][n] = x + relu(h*sc+sh)  (LDS transpose of h[n][o])
__global__ void k_final(const float* __restrict__ x, const short* __restrict__ h,
                        const float* __restrict__ bnsc, const float* __restrict__ bnsh,
                        float* __restrict__ out){
  int b = blockIdx.z, c0 = blockIdx.y*64, n0 = blockIdx.x*64;
  int tid = threadIdx.x;
  __shared__ float ht[64][65];
  {
    int n = tid>>2, ii = tid&3;
    #pragma unroll
    for(int p = 0; p < 2; ++p){
      int coff = 32*p + 8*ii;
      bf16x8 hv = *(const bf16x8*)(h + ((size_t)(b*N_ + n0 + n))*C_ + c0 + coff);
      #pragma unroll
      for(int jq = 0; jq < 8; ++jq) ht[n][coff + jq] = bf2f(hv[jq]);
    }
  }
  __syncthreads();
  int c = tid>>2, i2 = tid&3;
  float sc = bnsc[c0 + c], sh = bnsh[c0 + c];
  const float* xr = x + ((size_t)b*C_ + c0 + c)*N_ + n0 + 16*i2;
  float* orow = out + ((size_t)b*C_ + c0 + c)*N_ + n0 + 16*i2;
  #pragma unroll
  for(int k = 0; k < 16; k += 4){
    f32x4 xv = *(const f32x4*)(xr + k);
    f32x4 ov;
    #pragma unroll
    for(int jq = 0; jq < 4; ++jq){
      float bn = ht[16*i2 + k + jq][c]*sc + sh;
      ov[jq] = xv[jq] + fmaxf(bn, 0.f);
    }
    *(f32x4*)(orow + k) = ov;
  }
}

extern "C" void kernel_launch(void* const* d_in, const int* in_sizes, int n_in,
                              void* d_out, int out_size, void* d_ws, size_t ws_size,
                              hipStream_t stream){
  const float* x     = (const float*)d_in[0];
  const float* Wq    = (const float*)d_in[1];
  const float* Wk    = (const float*)d_in[2];
  const float* Wv    = (const float*)d_in[3];
  const float* Wl    = (const float*)d_in[4];
  const float* gamma = (const float*)d_in[5];
  const float* beta  = (const float*)d_in[6];
  float* out = (float*)d_out;

  char* p = (char*)d_ws;
  double* g    = (double*)p; p += (size_t)B_*C_*8;
  double* xsum = (double*)p; p += (size_t)B_*C_*8;
  short* Wb   = (short*)p;  p += (size_t)384*C_*2;
  short* Wlf  = (short*)p;  p += (size_t)C_*C_*2;
  short* qbuf = (short*)p;  p += (size_t)B_*N_*64*2;
  short* kf   = (short*)p;  p += (size_t)B_*N_*64*2;
  short* vf   = (short*)p;  p += (size_t)B_*C_*N_*2;
  short* xTb  = (short*)p;  p += (size_t)B_*N_*C_*2;
  short* att  = (short*)p;  p += (size_t)B_*N_*C_*2;
  float* part = (float*)p;  p += (size_t)512*512*4;
  float* bnsc = (float*)p;  p += C_*4;
  float* bnsh = (float*)p;  p += C_*4;
  short* h = vf;   // alias: vf fully consumed by k_attn before k_hgemm writes h

  k_convw  <<<384, 256, 0, stream>>>(Wq, Wk, Wv, Wl, Wb, Wlf);
  k_xsum   <<<dim3(C_/4, B_), 256, 0, stream>>>(x, xsum);
  k_prep_g2<<<B_, 256, 0, stream>>>(xsum, Wq, Wk, g);
  k_qkv    <<<dim3(N_/64, B_), 256, 0, stream>>>(x, Wb, g, qbuf, kf, vf, xTb);
  k_attn   <<<512, 256, 0, stream>>>(qbuf, kf, vf, att);
  k_hgemm  <<<dim3(N_/64, B_), 256, 0, stream>>>(xTb, att, Wlf, h, part);
  k_bnfin  <<<1, 1024, 0, stream>>>(part, gamma, beta, bnsc, bnsh);
  k_final  <<<dim3(N_/64, C_/64, B_), 256, 0, stream>>>(x, h, bnsc, bnsh, out);
}